// Round 1
// baseline (325.255 us; speedup 1.0000x reference)
//
#include <hip/hip_runtime.h>
#include <cstdint>
#include <cstddef>

#define BATCH 16384
#define VOCAB_MASK (4194304 - 1)

typedef __attribute__((ext_vector_type(4))) float f32x4;
typedef __attribute__((ext_vector_type(8))) __bf16 bf16x8;

static_assert(sizeof(bf16x8) == 16, "bf16x8 must be 16 bytes");

static __device__ __forceinline__ __bf16 f2bf(float f) {
  union { float f; unsigned u; } in; in.f = f;
  unsigned r = in.u + 0x7FFF + ((in.u >> 16) & 1);
  union { unsigned short s; __bf16 b; } out; out.s = (unsigned short)(r >> 16);
  return out.b;
}
static __device__ __forceinline__ float bf2f(__bf16 b) {
  union { __bf16 b; unsigned short s; } in; in.b = b;
  union { unsigned u; float f; } out; out.u = ((unsigned)in.s) << 16;
  return out.f;
}

// ---------------- weight transpose + bf16 convert: WT[n][k] = W[k][n] ----------------
__global__ void transpose_w(const float* __restrict__ W, __bf16* __restrict__ WT,
                            int K, int N, int Kp)
{
  int idx = blockIdx.x * 256 + threadIdx.x;
  if (idx >= N * Kp) return;
  int n = idx / Kp, k = idx - n * Kp;
  float v = (k < K) ? W[(size_t)k * N + n] : 0.f;
  WT[idx] = f2bf(v);
}

// ---------------- GEMM: C = relu(A @ W + bias), bf16 MFMA, 128x128 tile ----------------
// A: M x sA (bf16, or fp32 when A_F32=1; k >= Kb reads as 0)
// WT: N x Kp bf16 (pre-transposed, zero-padded)
// C: M x N bf16
template<int A_F32>
__global__ __launch_bounds__(256) void gemm_kernel(
    const void* __restrict__ Aptr, const __bf16* __restrict__ WT,
    const float* __restrict__ bias, __bf16* __restrict__ C,
    int N, int sA, int Kb, int Kp)
{
  __shared__ __bf16 As[128][40];   // +8 pad: row stride 80B (16B aligned, bank-spread)
  __shared__ __bf16 Bs[128][40];
  const int tid  = threadIdx.x;
  const int lane = tid & 63;
  const int wid  = tid >> 6;
  const int wr = wid >> 1, wc = wid & 1;      // 2x2 wave grid, 64x64 per wave
  const int m0 = blockIdx.x * 128, n0 = blockIdx.y * 128;
  const int lrow = tid >> 2;                   // 0..63
  const int lkk  = (tid & 3) * 8;              // 0,8,16,24

  f32x4 acc[4][4] = {};

  for (int k0 = 0; k0 < Kp; k0 += 32) {
    __syncthreads();
    #pragma unroll
    for (int it = 0; it < 2; ++it) {
      int row = lrow + it * 64;
      if (A_F32) {
        const float* A = (const float*)Aptr;
        #pragma unroll
        for (int j = 0; j < 8; ++j) {
          int k = k0 + lkk + j;
          float v = (k < Kb) ? A[(size_t)(m0 + row) * sA + k] : 0.f;
          As[row][lkk + j] = f2bf(v);
        }
      } else {
        const __bf16* A = (const __bf16*)Aptr;
        *(bf16x8*)&As[row][lkk] = *(const bf16x8*)&A[(size_t)(m0 + row) * sA + k0 + lkk];
      }
      *(bf16x8*)&Bs[row][lkk] = *(const bf16x8*)&WT[(size_t)(n0 + row) * Kp + k0 + lkk];
    }
    __syncthreads();

    bf16x8 af[4], bfv[4];
    #pragma unroll
    for (int m = 0; m < 4; ++m)
      af[m] = *(const bf16x8*)&As[wr * 64 + m * 16 + (lane & 15)][(lane >> 4) * 8];
    #pragma unroll
    for (int n = 0; n < 4; ++n)
      bfv[n] = *(const bf16x8*)&Bs[wc * 64 + n * 16 + (lane & 15)][(lane >> 4) * 8];
    #pragma unroll
    for (int m = 0; m < 4; ++m)
      #pragma unroll
      for (int n = 0; n < 4; ++n)
        acc[m][n] = __builtin_amdgcn_mfma_f32_16x16x32_bf16(af[m], bfv[n], acc[m][n], 0, 0, 0);
  }

  // epilogue: bias + relu, store bf16. D layout: col=lane&15, row=(lane>>4)*4+r (m89-verified)
  #pragma unroll
  for (int m = 0; m < 4; ++m)
    #pragma unroll
    for (int n = 0; n < 4; ++n) {
      int col = n0 + wc * 64 + n * 16 + (lane & 15);
      float bv = bias[col];
      #pragma unroll
      for (int r = 0; r < 4; ++r) {
        int row = m0 + wr * 64 + m * 16 + (lane >> 4) * 4 + r;
        float v = acc[m][n][r] + bv;
        v = fmaxf(v, 0.f);
        C[(size_t)row * N + col] = f2bf(v);
      }
    }
}

// ---------------- embedding gather + pairwise interaction ----------------
// top_in[b] = [bot_out(128) | triu(stack@stackT)(378) | zeros(6)]  (512 bf16)
__global__ __launch_bounds__(384) void interact_kernel(
    const __bf16* __restrict__ bot, const int* __restrict__ xcat,
    const float* __restrict__ emb, __bf16* __restrict__ top_in)
{
  __shared__ float s[27][132];   // row stride 132: 16B aligned, 33 words ≡ 1 mod 32 banks
  __shared__ int rows_s[26];
  const int b = blockIdx.x;
  const int tid = threadIdx.x;

  if (tid < 26) rows_s[tid] = xcat[(size_t)b * 26 + tid] & VOCAB_MASK;
  __syncthreads();

  // stage stack: row 0 = bot_out[b], rows 1..26 = embedding rows (fp32)
  for (int idx = tid; idx < 27 * 128; idx += 384) {
    int r = idx >> 7, d = idx & 127;
    float v;
    if (r == 0) v = bf2f(bot[(size_t)b * 128 + d]);
    else        v = emb[(size_t)rows_s[r - 1] * 128 + d];
    s[r][d] = v;
  }
  __syncthreads();

  // copy bot_out to cols 0..127
  for (int d = tid; d < 128; d += 384)
    top_in[(size_t)b * 512 + d] = f2bf(s[0][d]);

  // 378 upper-triangle dot products (i<=j, row-major triu order)
  int p = tid;
  if (p < 378) {
    int i = 0, rem = p, len = 27;
    while (rem >= len) { rem -= len; --len; ++i; }
    int j = i + rem;
    const float* si = s[i];
    const float* sj = s[j];
    float acc = 0.f;
    #pragma unroll
    for (int d = 0; d < 128; d += 4) {
      f32x4 a = *(const f32x4*)&si[d];
      f32x4 c = *(const f32x4*)&sj[d];
      acc += a.x * c.x + a.y * c.y + a.z * c.z + a.w * c.w;
    }
    top_in[(size_t)b * 512 + 128 + p] = f2bf(acc);
  } else {
    // p in [378,384): zero-pad cols 506..511
    top_in[(size_t)b * 512 + 128 + p] = f2bf(0.f);
  }
}

// ---------------- final layer: out[b] = dot(t3[b], w4) + b4 (no relu) ----------------
__global__ __launch_bounds__(256) void final_kernel(
    const __bf16* __restrict__ t3, const float* __restrict__ w4,
    const float* __restrict__ b4, float* __restrict__ out)
{
  int row  = blockIdx.x * 4 + (threadIdx.x >> 6);
  int lane = threadIdx.x & 63;
  const __bf16* tr = &t3[(size_t)row * 256 + lane * 4];
  float acc = 0.f;
  #pragma unroll
  for (int j = 0; j < 4; ++j) acc += bf2f(tr[j]) * w4[lane * 4 + j];
  #pragma unroll
  for (int off = 32; off; off >>= 1) acc += __shfl_down(acc, off);
  if (lane == 0) out[row] = acc + b4[0];
}

extern "C" void kernel_launch(void* const* d_in, const int* in_sizes, int n_in,
                              void* d_out, int out_size, void* d_ws, size_t ws_size,
                              hipStream_t stream)
{
  const float* x_dense = (const float*)d_in[0];
  const int*   x_cat   = (const int*)d_in[1];
  const float* emb     = (const float*)d_in[2];
  const float* wb[3] = {(const float*)d_in[3], (const float*)d_in[5], (const float*)d_in[7]};
  const float* bb[3] = {(const float*)d_in[4], (const float*)d_in[6], (const float*)d_in[8]};
  const float* wt[5] = {(const float*)d_in[9],  (const float*)d_in[11], (const float*)d_in[13],
                        (const float*)d_in[15], (const float*)d_in[17]};
  const float* bt[5] = {(const float*)d_in[10], (const float*)d_in[12], (const float*)d_in[14],
                        (const float*)d_in[16], (const float*)d_in[18]};
  float* out = (float*)d_out;

  char* ws = (char*)d_ws;
  const size_t MB = 1ull << 20;
  // weights (bf16, transposed, K zero-padded): 8MB region
  __bf16* wt_b0 = (__bf16*)(ws + 0 * MB);   // 512x32
  __bf16* wt_b1 = (__bf16*)(ws + 1 * MB);   // 256x512
  __bf16* wt_b2 = (__bf16*)(ws + 2 * MB);   // 128x256
  __bf16* wt_t0 = (__bf16*)(ws + 3 * MB);   // 1024x512
  __bf16* wt_t1 = (__bf16*)(ws + 4 * MB);   // 1024x1024
  __bf16* wt_t2 = (__bf16*)(ws + 6 * MB);   // 512x1024
  __bf16* wt_t3 = (__bf16*)(ws + 7 * MB);   // 256x512
  // activations (bf16), aliased regions (total ws use = 92MB):
  __bf16* h2     = (__bf16*)(ws + 8 * MB);   // 16384x128 = 4MB
  __bf16* top_in = (__bf16*)(ws + 12 * MB);  // 16384x512 = 16MB  (region C)
  __bf16* t2     = (__bf16*)(ws + 12 * MB);  //                   (region C, after top_in dead)
  __bf16* h0     = (__bf16*)(ws + 28 * MB);  // 16384x512 = 16MB  (region A)
  __bf16* t1     = (__bf16*)(ws + 28 * MB);  // 16384x1024= 32MB  (region A, after h0 dead)
  __bf16* t3     = (__bf16*)(ws + 28 * MB);  // 16384x256 = 8MB   (region A, after t1 dead)
  __bf16* h1     = (__bf16*)(ws + 60 * MB);  // 16384x256 = 8MB   (region B)
  __bf16* t0     = (__bf16*)(ws + 60 * MB);  // 16384x1024= 32MB  (region B, after h1 dead)

  // ---- weight prep ----
  auto T = [&](const float* W, __bf16* WTp, int K, int N, int Kp) {
    int tot = N * Kp;
    transpose_w<<<dim3((tot + 255) / 256), dim3(256), 0, stream>>>(W, WTp, K, N, Kp);
  };
  T(wb[0], wt_b0, 13,   512,  32);
  T(wb[1], wt_b1, 512,  256,  512);
  T(wb[2], wt_b2, 256,  128,  256);
  T(wt[0], wt_t0, 506,  1024, 512);
  T(wt[1], wt_t1, 1024, 1024, 1024);
  T(wt[2], wt_t2, 1024, 512,  1024);
  T(wt[3], wt_t3, 512,  256,  512);

  // ---- bottom MLP ----
  gemm_kernel<1><<<dim3(128, 4), dim3(256), 0, stream>>>(x_dense, wt_b0, bb[0], h0, 512, 13, 13, 32);
  gemm_kernel<0><<<dim3(128, 2), dim3(256), 0, stream>>>(h0, wt_b1, bb[1], h1, 256, 512, 512, 512);
  gemm_kernel<0><<<dim3(128, 1), dim3(256), 0, stream>>>(h1, wt_b2, bb[2], h2, 128, 256, 256, 256);

  // ---- embedding + interaction ----
  interact_kernel<<<dim3(BATCH), dim3(384), 0, stream>>>(h2, x_cat, emb, top_in);

  // ---- top MLP ----
  gemm_kernel<0><<<dim3(128, 8), dim3(256), 0, stream>>>(top_in, wt_t0, bt[0], t0, 1024, 512, 512, 512);
  gemm_kernel<0><<<dim3(128, 8), dim3(256), 0, stream>>>(t0, wt_t1, bt[1], t1, 1024, 1024, 1024, 1024);
  gemm_kernel<0><<<dim3(128, 4), dim3(256), 0, stream>>>(t1, wt_t2, bt[2], t2, 512, 1024, 1024, 1024);
  gemm_kernel<0><<<dim3(128, 2), dim3(256), 0, stream>>>(t2, wt_t3, bt[3], t3, 256, 512, 512, 512);

  // ---- final dot (N=1, no relu) ----
  final_kernel<<<dim3(BATCH / 4), dim3(256), 0, stream>>>(t3, wt[4], bt[4], out);
}

// Round 2
// 281.649 us; speedup vs baseline: 1.1548x; 1.1548x over previous
//
#include <hip/hip_runtime.h>
#include <cstdint>
#include <cstddef>

#define BATCH 16384
#define VOCAB_MASK (4194304 - 1)

typedef __attribute__((ext_vector_type(4))) float f32x4;
typedef __attribute__((ext_vector_type(8))) __bf16 bf16x8;

static_assert(sizeof(bf16x8) == 16, "bf16x8 must be 16 bytes");

static __device__ __forceinline__ __bf16 f2bf(float f) {
  union { float f; unsigned u; } in; in.f = f;
  unsigned r = in.u + 0x7FFF + ((in.u >> 16) & 1);
  union { unsigned short s; __bf16 b; } out; out.s = (unsigned short)(r >> 16);
  return out.b;
}
static __device__ __forceinline__ float bf2f(__bf16 b) {
  union { __bf16 b; unsigned short s; } in; in.b = b;
  union { unsigned u; float f; } out; out.u = ((unsigned)in.s) << 16;
  return out.f;
}

// async global->LDS, 16B per lane. LDS dest must be wave-uniform base + lane*16.
#define GLDS16(g, l) __builtin_amdgcn_global_load_lds( \
    (const __attribute__((address_space(1))) unsigned int*)(g), \
    (__attribute__((address_space(3))) unsigned int*)(l), 16, 0, 0)

// ---------------- tiled weight transpose + bf16 convert: WT[n][k] = W[k][n] ----------------
__global__ __launch_bounds__(256) void transpose_w(
    const float* __restrict__ W, __bf16* __restrict__ WT, int K, int N, int Kp)
{
  __shared__ float tile[64][65];
  const int kb = blockIdx.x * 64, nb = blockIdx.y * 64;
  const int tx = threadIdx.x & 63, ty = threadIdx.x >> 6;  // ty in 0..3
  #pragma unroll
  for (int i = 0; i < 64; i += 4) {
    int k = kb + ty + i, n = nb + tx;
    tile[ty + i][tx] = (k < K && n < N) ? W[(size_t)k * N + n] : 0.f;
  }
  __syncthreads();
  #pragma unroll
  for (int i = 0; i < 64; i += 4) {
    int n = nb + ty + i, k = kb + tx;
    if (n < N && k < Kp) WT[(size_t)n * Kp + k] = f2bf(tile[tx][ty + i]);
  }
}

// ---------------- GEMM (bf16 A): C = relu(A @ W + bias), m97 structure ----------------
// A: M x sA bf16 row-major; WT: N x Kp bf16; C: M x N bf16. Kp % 32 == 0.
__global__ __launch_bounds__(256) void gemm_glds(
    const __bf16* __restrict__ A, const __bf16* __restrict__ WT,
    const float* __restrict__ bias, __bf16* __restrict__ C,
    int N, int sA, int Kp)
{
  __shared__ __bf16 As[128][32];   // linear: global_load_lds needs contiguous dest
  __shared__ __bf16 Bs[128][32];
  const int tid  = threadIdx.x;
  const int lane = tid & 63;
  const int wid  = tid >> 6;
  const int wr = wid >> 1, wc = wid & 1;
  const int m0 = blockIdx.x * 128, n0 = blockIdx.y * 128;

  // staging map: per call, wave wid fills 16 rows (1KB). lane l -> row wid*16 + l/4, col (l&3)*8
  const int srow = wid * 16 + (lane >> 2);
  const int scol = (lane & 3) * 8;
  const __bf16* Ag0 = A  + (size_t)(m0 + srow)      * sA + scol;
  const __bf16* Ag1 = A  + (size_t)(m0 + srow + 64) * sA + scol;
  const __bf16* Bg0 = WT + (size_t)(n0 + srow)      * Kp + scol;
  const __bf16* Bg1 = WT + (size_t)(n0 + srow + 64) * Kp + scol;
  __bf16* lA0 = &As[srow][scol];
  __bf16* lA1 = &As[srow + 64][scol];
  __bf16* lB0 = &Bs[srow][scol];
  __bf16* lB1 = &Bs[srow + 64][scol];

  f32x4 acc[4][4] = {};

  for (int k0 = 0; k0 < Kp; k0 += 32) {
    __syncthreads();              // previous compute done before overwrite
    GLDS16(Ag0 + k0, lA0);
    GLDS16(Ag1 + k0, lA1);
    GLDS16(Bg0 + k0, lB0);
    GLDS16(Bg1 + k0, lB1);
    __syncthreads();              // drains vmcnt, tile ready

    bf16x8 af[4], bfv[4];
    #pragma unroll
    for (int m = 0; m < 4; ++m)
      af[m] = *(const bf16x8*)&As[wr * 64 + m * 16 + (lane & 15)][(lane >> 4) * 8];
    #pragma unroll
    for (int n = 0; n < 4; ++n)
      bfv[n] = *(const bf16x8*)&Bs[wc * 64 + n * 16 + (lane & 15)][(lane >> 4) * 8];
    #pragma unroll
    for (int m = 0; m < 4; ++m)
      #pragma unroll
      for (int n = 0; n < 4; ++n)
        acc[m][n] = __builtin_amdgcn_mfma_f32_16x16x32_bf16(af[m], bfv[n], acc[m][n], 0, 0, 0);
  }

  #pragma unroll
  for (int m = 0; m < 4; ++m)
    #pragma unroll
    for (int n = 0; n < 4; ++n) {
      int col = n0 + wc * 64 + n * 16 + (lane & 15);
      float bv = bias[col];
      #pragma unroll
      for (int r = 0; r < 4; ++r) {
        int row = m0 + wr * 64 + m * 16 + (lane >> 4) * 4 + r;
        float v = fmaxf(acc[m][n][r] + bv, 0.f);
        C[(size_t)row * N + col] = f2bf(v);
      }
    }
}

// ---------------- GEMM (fp32 A, K<=32 single step): bottom layer 0 ----------------
__global__ __launch_bounds__(256) void gemm_f32a(
    const float* __restrict__ A, const __bf16* __restrict__ WT,
    const float* __restrict__ bias, __bf16* __restrict__ C,
    int N, int sA, int Kb, int Kp)
{
  __shared__ __bf16 As[128][40];
  __shared__ __bf16 Bs[128][40];
  const int tid  = threadIdx.x;
  const int lane = tid & 63;
  const int wid  = tid >> 6;
  const int wr = wid >> 1, wc = wid & 1;
  const int m0 = blockIdx.x * 128, n0 = blockIdx.y * 128;
  const int lrow = tid >> 2;
  const int lkk  = (tid & 3) * 8;

  f32x4 acc[4][4] = {};

  for (int k0 = 0; k0 < Kp; k0 += 32) {
    __syncthreads();
    #pragma unroll
    for (int it = 0; it < 2; ++it) {
      int row = lrow + it * 64;
      #pragma unroll
      for (int j = 0; j < 8; ++j) {
        int k = k0 + lkk + j;
        float v = (k < Kb) ? A[(size_t)(m0 + row) * sA + k] : 0.f;
        As[row][lkk + j] = f2bf(v);
      }
      *(bf16x8*)&Bs[row][lkk] = *(const bf16x8*)&WT[(size_t)(n0 + row) * Kp + k0 + lkk];
    }
    __syncthreads();

    bf16x8 af[4], bfv[4];
    #pragma unroll
    for (int m = 0; m < 4; ++m)
      af[m] = *(const bf16x8*)&As[wr * 64 + m * 16 + (lane & 15)][(lane >> 4) * 8];
    #pragma unroll
    for (int n = 0; n < 4; ++n)
      bfv[n] = *(const bf16x8*)&Bs[wc * 64 + n * 16 + (lane & 15)][(lane >> 4) * 8];
    #pragma unroll
    for (int m = 0; m < 4; ++m)
      #pragma unroll
      for (int n = 0; n < 4; ++n)
        acc[m][n] = __builtin_amdgcn_mfma_f32_16x16x32_bf16(af[m], bfv[n], acc[m][n], 0, 0, 0);
  }

  #pragma unroll
  for (int m = 0; m < 4; ++m)
    #pragma unroll
    for (int n = 0; n < 4; ++n) {
      int col = n0 + wc * 64 + n * 16 + (lane & 15);
      float bv = bias[col];
      #pragma unroll
      for (int r = 0; r < 4; ++r) {
        int row = m0 + wr * 64 + m * 16 + (lane >> 4) * 4 + r;
        float v = fmaxf(acc[m][n][r] + bv, 0.f);
        C[(size_t)row * N + col] = f2bf(v);
      }
    }
}

// ---------------- embedding gather + MFMA pairwise interaction ----------------
// 1 wave per sample, 4 samples per block. Gram(27x27) via 16x16x32 bf16 MFMA,
// A and B fragments are the same LDS reads (S . S^T symmetric); skip (1,0) quadrant.
__global__ __launch_bounds__(256) void interact_mfma(
    const __bf16* __restrict__ bot, const int* __restrict__ xcat,
    const float* __restrict__ emb, __bf16* __restrict__ top_in)
{
  __shared__ __bf16 st[4][32][136];   // row stride 272B: 16B-aligned, 2-way banks (free)
  const int tid = threadIdx.x, lane = tid & 63, w = tid >> 6;
  const int s = blockIdx.x * 4 + w;

  // row 0: bot_out (already bf16)
  {
    const __bf16* bp = bot + (size_t)s * 128 + lane * 2;
    st[w][0][lane * 2]     = bp[0];
    st[w][0][lane * 2 + 1] = bp[1];
  }
  // rows 1..26: embedding rows (fp32 -> bf16), coalesced float2 per lane
  const int* xr = xcat + (size_t)s * 26;
  #pragma unroll
  for (int r = 1; r < 27; ++r) {
    int ridx = xr[r - 1] & VOCAB_MASK;
    float2 v = *(const float2*)(emb + (size_t)ridx * 128 + lane * 2);
    st[w][r][lane * 2]     = f2bf(v.x);
    st[w][r][lane * 2 + 1] = f2bf(v.y);
  }
  // rows 27..31: zero pad
  #pragma unroll
  for (int r = 27; r < 32; ++r) {
    st[w][r][lane * 2]     = f2bf(0.f);
    st[w][r][lane * 2 + 1] = f2bf(0.f);
  }

  f32x4 a00 = {}, a01 = {}, a11 = {};
  #pragma unroll
  for (int k0 = 0; k0 < 4; ++k0) {
    bf16x8 fr0 = *(const bf16x8*)&st[w][(lane & 15)][k0 * 32 + (lane >> 4) * 8];
    bf16x8 fr1 = *(const bf16x8*)&st[w][16 + (lane & 15)][k0 * 32 + (lane >> 4) * 8];
    a00 = __builtin_amdgcn_mfma_f32_16x16x32_bf16(fr0, fr0, a00, 0, 0, 0);
    a01 = __builtin_amdgcn_mfma_f32_16x16x32_bf16(fr0, fr1, a01, 0, 0, 0);
    a11 = __builtin_amdgcn_mfma_f32_16x16x32_bf16(fr1, fr1, a11, 0, 0, 0);
  }

  __bf16* op = top_in + (size_t)s * 512;
  // cols 0..127 = bot_out
  op[lane * 2]     = st[w][0][lane * 2];
  op[lane * 2 + 1] = st[w][0][lane * 2 + 1];
  // cols 506..511 = 0
  if (lane < 6) op[506 + lane] = f2bf(0.f);

  // triu extraction: D layout col=lane&15, row=(lane>>4)*4+r
  const int jc = lane & 15, rb = (lane >> 4) * 4;
  #pragma unroll
  for (int r = 0; r < 4; ++r) {
    // quadrant (0,0): i in 0..15, j in 0..15
    {
      int i = rb + r, j = jc;
      if (i <= j) op[128 + i * 27 - i * (i - 1) / 2 + (j - i)] = f2bf(a00[r]);
    }
    // quadrant (0,1): i in 0..15, j in 16..31
    {
      int i = rb + r, j = 16 + jc;
      if (j <= 26) op[128 + i * 27 - i * (i - 1) / 2 + (j - i)] = f2bf(a01[r]);
    }
    // quadrant (1,1): i in 16..31, j in 16..31
    {
      int i = 16 + rb + r, j = 16 + jc;
      if (i <= j && j <= 26) op[128 + i * 27 - i * (i - 1) / 2 + (j - i)] = f2bf(a11[r]);
    }
  }
}

// ---------------- final layer: out[b] = dot(t3[b], w4) + b4 (no relu) ----------------
__global__ __launch_bounds__(256) void final_kernel(
    const __bf16* __restrict__ t3, const float* __restrict__ w4,
    const float* __restrict__ b4, float* __restrict__ out)
{
  int row  = blockIdx.x * 4 + (threadIdx.x >> 6);
  int lane = threadIdx.x & 63;
  const __bf16* tr = &t3[(size_t)row * 256 + lane * 4];
  float acc = 0.f;
  #pragma unroll
  for (int j = 0; j < 4; ++j) acc += bf2f(tr[j]) * w4[lane * 4 + j];
  #pragma unroll
  for (int off = 32; off; off >>= 1) acc += __shfl_down(acc, off);
  if (lane == 0) out[row] = acc + b4[0];
}

extern "C" void kernel_launch(void* const* d_in, const int* in_sizes, int n_in,
                              void* d_out, int out_size, void* d_ws, size_t ws_size,
                              hipStream_t stream)
{
  const float* x_dense = (const float*)d_in[0];
  const int*   x_cat   = (const int*)d_in[1];
  const float* emb     = (const float*)d_in[2];
  const float* wb[3] = {(const float*)d_in[3], (const float*)d_in[5], (const float*)d_in[7]};
  const float* bb[3] = {(const float*)d_in[4], (const float*)d_in[6], (const float*)d_in[8]};
  const float* wt[5] = {(const float*)d_in[9],  (const float*)d_in[11], (const float*)d_in[13],
                        (const float*)d_in[15], (const float*)d_in[17]};
  const float* bt[5] = {(const float*)d_in[10], (const float*)d_in[12], (const float*)d_in[14],
                        (const float*)d_in[16], (const float*)d_in[18]};
  float* out = (float*)d_out;

  char* ws = (char*)d_ws;
  const size_t MB = 1ull << 20;
  __bf16* wt_b0 = (__bf16*)(ws + 0 * MB);   // 512x32
  __bf16* wt_b1 = (__bf16*)(ws + 1 * MB);   // 256x512
  __bf16* wt_b2 = (__bf16*)(ws + 2 * MB);   // 128x256
  __bf16* wt_t0 = (__bf16*)(ws + 3 * MB);   // 1024x512
  __bf16* wt_t1 = (__bf16*)(ws + 4 * MB);   // 1024x1024
  __bf16* wt_t2 = (__bf16*)(ws + 6 * MB);   // 512x1024
  __bf16* wt_t3 = (__bf16*)(ws + 7 * MB);   // 256x512
  __bf16* h2     = (__bf16*)(ws + 8 * MB);   // 16384x128 = 4MB
  __bf16* top_in = (__bf16*)(ws + 12 * MB);  // 16384x512 = 16MB  (region C)
  __bf16* t2     = (__bf16*)(ws + 12 * MB);  //                   (region C, after top_in dead)
  __bf16* h0     = (__bf16*)(ws + 28 * MB);  // 16384x512 = 16MB  (region A)
  __bf16* t1     = (__bf16*)(ws + 28 * MB);  // 16384x1024= 32MB  (region A, after h0 dead)
  __bf16* t3     = (__bf16*)(ws + 28 * MB);  // 16384x256 = 8MB   (region A, after t1 dead)
  __bf16* h1     = (__bf16*)(ws + 60 * MB);  // 16384x256 = 8MB   (region B)
  __bf16* t0     = (__bf16*)(ws + 60 * MB);  // 16384x1024= 32MB  (region B, after h1 dead)

  auto T = [&](const float* W, __bf16* WTp, int K, int N, int Kp) {
    transpose_w<<<dim3((Kp + 63) / 64, (N + 63) / 64), dim3(256), 0, stream>>>(W, WTp, K, N, Kp);
  };
  T(wb[0], wt_b0, 13,   512,  32);
  T(wb[1], wt_b1, 512,  256,  512);
  T(wb[2], wt_b2, 256,  128,  256);
  T(wt[0], wt_t0, 506,  1024, 512);
  T(wt[1], wt_t1, 1024, 1024, 1024);
  T(wt[2], wt_t2, 1024, 512,  1024);
  T(wt[3], wt_t3, 512,  256,  512);

  // ---- bottom MLP ----
  gemm_f32a<<<dim3(128, 4), dim3(256), 0, stream>>>(x_dense, wt_b0, bb[0], h0, 512, 13, 13, 32);
  gemm_glds<<<dim3(128, 2), dim3(256), 0, stream>>>(h0, wt_b1, bb[1], h1, 256, 512, 512);
  gemm_glds<<<dim3(128, 1), dim3(256), 0, stream>>>(h1, wt_b2, bb[2], h2, 128, 256, 256);

  // ---- embedding + interaction ----
  interact_mfma<<<dim3(BATCH / 4), dim3(256), 0, stream>>>(h2, x_cat, emb, top_in);

  // ---- top MLP ----
  gemm_glds<<<dim3(128, 8), dim3(256), 0, stream>>>(top_in, wt_t0, bt[0], t0, 1024, 512, 512);
  gemm_glds<<<dim3(128, 8), dim3(256), 0, stream>>>(t0, wt_t1, bt[1], t1, 1024, 1024, 1024);
  gemm_glds<<<dim3(128, 4), dim3(256), 0, stream>>>(t1, wt_t2, bt[2], t2, 512, 1024, 1024);
  gemm_glds<<<dim3(128, 2), dim3(256), 0, stream>>>(t2, wt_t3, bt[3], t3, 256, 512, 512);

  // ---- final dot ----
  final_kernel<<<dim3(BATCH / 4), dim3(256), 0, stream>>>(t3, wt[4], bt[4], out);
}

// Round 4
// 214.644 us; speedup vs baseline: 1.5153x; 1.3122x over previous
//
#include <hip/hip_runtime.h>
#include <cstdint>
#include <cstddef>

#define BATCH 16384
#define VOCAB_MASK (4194304 - 1)

typedef __attribute__((ext_vector_type(4))) float f32x4;
typedef __attribute__((ext_vector_type(8))) __bf16 bf16x8;

static_assert(sizeof(bf16x8) == 16, "bf16x8 must be 16 bytes");

static __device__ __forceinline__ __bf16 f2bf(float f) {
  union { float f; unsigned u; } in; in.f = f;
  unsigned r = in.u + 0x7FFF + ((in.u >> 16) & 1);
  union { unsigned short s; __bf16 b; } out; out.s = (unsigned short)(r >> 16);
  return out.b;
}
static __device__ __forceinline__ float bf2f(__bf16 b) {
  union { __bf16 b; unsigned short s; } in; in.b = b;
  union { unsigned u; float f; } out; out.u = ((unsigned)in.s) << 16;
  return out.f;
}

// async global->LDS, 16B per lane. LDS dest must be wave-uniform base + lane*16.
#define GLDS16(g, l) __builtin_amdgcn_global_load_lds( \
    (const __attribute__((address_space(1))) unsigned int*)(g), \
    (__attribute__((address_space(3))) unsigned int*)(l), 16, 0, 0)

// swizzle: XOR 16B-chunk index bits (involution within 1KB block)
static __device__ __forceinline__ unsigned swz16(unsigned b) {
  return b ^ ((((b >> 6) & 3u) ^ ((b >> 8) & 3u)) << 4);
}
// swizzled LDS fragment read: row r (64B rows), 16B group cg, region base `base`
static __device__ __forceinline__ bf16x8 lds_frag(const char* smem, unsigned base,
                                                  unsigned r, unsigned cg) {
  unsigned b = r * 64u + cg;
  return *(const bf16x8*)(smem + base + swz16(b));
}

// ---------------- fused weight transpose + bf16 convert: WT[n][k] = W[k][n] ----------------
struct TJob { const float* W; __bf16* WT; int K, N, Kp, tx, off; };
struct TJobs { TJob j[7]; };

__global__ __launch_bounds__(256) void transpose_all(TJobs js, int njobs)
{
  __shared__ float tile[64][65];
  int b = blockIdx.x;
  int ji = 0;
  #pragma unroll
  for (int i = 1; i < 7; ++i) if (i < njobs && b >= js.j[i].off) ji = i;
  const TJob jb = js.j[ji];
  int lb = b - jb.off;
  int bx = lb % jb.tx, by = lb / jb.tx;
  const int kb = bx * 64, nb = by * 64;
  const int tx = threadIdx.x & 63, ty = threadIdx.x >> 6;
  #pragma unroll
  for (int i = 0; i < 64; i += 4) {
    int k = kb + ty + i, n = nb + tx;
    tile[ty + i][tx] = (k < jb.K && n < jb.N) ? jb.W[(size_t)k * jb.N + n] : 0.f;
  }
  __syncthreads();
  #pragma unroll
  for (int i = 0; i < 64; i += 4) {
    int n = nb + ty + i, k = kb + tx;
    if (n < jb.N && k < jb.Kp) jb.WT[(size_t)n * jb.Kp + k] = f2bf(tile[tx][ty + i]);
  }
}

// ---------------- 256x256 phase-interleaved GEMM (T2+T3+T4+T5), BK=32 ----------------
// C = relu(A @ WT^T + bias). M%256==0, N%256==0, K%64==0. 512 threads, 8 waves (2Mx4N).
// LDS 64KB: buf p: A-tile[256][32] @ p*32768, B-tile[256][32] @ p*32768+16384.
__global__ __launch_bounds__(512, 2) void gemm_8ph(
    const __bf16* __restrict__ A, const __bf16* __restrict__ WT,
    const float* __restrict__ bias, __bf16* __restrict__ C,
    int N, int sA, int K, int gm)
{
  __shared__ __align__(16) char smem[65536];
  const int tid = threadIdx.x, lane = tid & 63, w = tid >> 6;
  const int wm = w >> 2, wn = w & 3;       // 2x4 wave grid; wave tile 128(M) x 64(N)

  // T1: bijective XCD swizzle (grid % 8 == 0 for our shapes)
  int nb = gridDim.x;
  int id = blockIdx.x;
  int swz = ((nb & 7) == 0) ? ((id & 7) * (nb >> 3) + (id >> 3)) : id;
  const int m0 = (swz % gm) * 256, n0 = (swz / gm) * 256;

  // staging source precompute (rule #21: linear LDS dest, inverse-swizzled global src)
  unsigned Ld[2]; const __bf16* sAp[2]; const __bf16* sBp[2];
  #pragma unroll
  for (int h = 0; h < 2; ++h) {
    unsigned L = h * 8192u + (unsigned)w * 1024u + (unsigned)lane * 16u;
    unsigned Ls = swz16(L);
    Ld[h] = L;
    int srow = Ls >> 6, scb = Ls & 63;
    sAp[h] = A  + (size_t)(m0 + srow) * sA + (scb >> 1);
    sBp[h] = WT + (size_t)(n0 + srow) * K  + (scb >> 1);
  }

  #define STAGE_A(kt, p) { GLDS16(sAp[0] + (kt)*32, smem + (p)*32768 + Ld[0]); \
                           GLDS16(sAp[1] + (kt)*32, smem + (p)*32768 + Ld[1]); }
  #define STAGE_B(kt, p) { GLDS16(sBp[0] + (kt)*32, smem + (p)*32768 + 16384 + Ld[0]); \
                           GLDS16(sBp[1] + (kt)*32, smem + (p)*32768 + 16384 + Ld[1]); }

  const unsigned cg = (lane >> 4) * 16u;   // 16B group within row
  const unsigned rA = (lane & 15);

  f32x4 acc[8][4] = {};
  const int KT = K >> 5;
  const int iters = KT >> 1;

  // prologue: B(t0), A(t0), B(t1); guard t0 resident (2 instr = B(t1) may fly)
  STAGE_B(0, 0); STAGE_A(0, 0); STAGE_B(1, 1);
  asm volatile("s_waitcnt vmcnt(2)" ::: "memory");
  __builtin_amdgcn_s_barrier();
  __builtin_amdgcn_sched_barrier(0);

  for (int i = 0; i < iters; ++i) {
    const int t = 2 * i;
    const bool more = (i + 1 < iters);

    // ---- ph0: tile t (buf0) qm0 ; stage A(t+1)->buf1-A ----
    bf16x8 a0[4], b0[4];
    #pragma unroll
    for (int m = 0; m < 4; ++m) a0[m] = lds_frag(smem, 0, wm * 128 + m * 16 + rA, cg);
    #pragma unroll
    for (int n = 0; n < 4; ++n) b0[n] = lds_frag(smem, 16384, wn * 64 + n * 16 + rA, cg);
    STAGE_A(t + 1, 1);
    __builtin_amdgcn_s_barrier();
    asm volatile("s_waitcnt lgkmcnt(0)" ::: "memory");
    __builtin_amdgcn_sched_barrier(0);
    __builtin_amdgcn_s_setprio(1);
    #pragma unroll
    for (int m = 0; m < 4; ++m)
      #pragma unroll
      for (int n = 0; n < 4; ++n)
        acc[m][n] = __builtin_amdgcn_mfma_f32_16x16x32_bf16(a0[m], b0[n], acc[m][n], 0, 0, 0);
    __builtin_amdgcn_s_setprio(0);
    __builtin_amdgcn_s_barrier();
    __builtin_amdgcn_sched_barrier(0);

    // ---- ph1: tile t qm1 ; stage B(t+2)->buf0-B ; guard tile t+1 ----
    bf16x8 a1[4];
    #pragma unroll
    for (int m = 0; m < 4; ++m) a1[m] = lds_frag(smem, 0, wm * 128 + 64 + m * 16 + rA, cg);
    if (more) STAGE_B(t + 2, 0);
    __builtin_amdgcn_s_barrier();
    asm volatile("s_waitcnt lgkmcnt(0)" ::: "memory");
    __builtin_amdgcn_sched_barrier(0);
    __builtin_amdgcn_s_setprio(1);
    #pragma unroll
    for (int m = 0; m < 4; ++m)
      #pragma unroll
      for (int n = 0; n < 4; ++n)
        acc[4 + m][n] = __builtin_amdgcn_mfma_f32_16x16x32_bf16(a1[m], b0[n], acc[4 + m][n], 0, 0, 0);
    __builtin_amdgcn_s_setprio(0);
    if (more) { asm volatile("s_waitcnt vmcnt(2)" ::: "memory"); }
    else      { asm volatile("s_waitcnt vmcnt(0)" ::: "memory"); }
    __builtin_amdgcn_s_barrier();
    __builtin_amdgcn_sched_barrier(0);

    // ---- ph2: tile t+1 (buf1) qm0 ; stage A(t+2)->buf0-A ----
    bf16x8 a2[4], b2[4];
    #pragma unroll
    for (int m = 0; m < 4; ++m) a2[m] = lds_frag(smem, 32768, wm * 128 + m * 16 + rA, cg);
    #pragma unroll
    for (int n = 0; n < 4; ++n) b2[n] = lds_frag(smem, 32768 + 16384, wn * 64 + n * 16 + rA, cg);
    if (more) STAGE_A(t + 2, 0);
    __builtin_amdgcn_s_barrier();
    asm volatile("s_waitcnt lgkmcnt(0)" ::: "memory");
    __builtin_amdgcn_sched_barrier(0);
    __builtin_amdgcn_s_setprio(1);
    #pragma unroll
    for (int m = 0; m < 4; ++m)
      #pragma unroll
      for (int n = 0; n < 4; ++n)
        acc[m][n] = __builtin_amdgcn_mfma_f32_16x16x32_bf16(a2[m], b2[n], acc[m][n], 0, 0, 0);
    __builtin_amdgcn_s_setprio(0);
    __builtin_amdgcn_s_barrier();
    __builtin_amdgcn_sched_barrier(0);

    // ---- ph3: tile t+1 qm1 ; stage B(t+3)->buf1-B ; guard tile t+2 ----
    bf16x8 a3[4];
    #pragma unroll
    for (int m = 0; m < 4; ++m) a3[m] = lds_frag(smem, 32768, wm * 128 + 64 + m * 16 + rA, cg);
    if (more) STAGE_B(t + 3, 1);
    __builtin_amdgcn_s_barrier();
    asm volatile("s_waitcnt lgkmcnt(0)" ::: "memory");
    __builtin_amdgcn_sched_barrier(0);
    __builtin_amdgcn_s_setprio(1);
    #pragma unroll
    for (int m = 0; m < 4; ++m)
      #pragma unroll
      for (int n = 0; n < 4; ++n)
        acc[4 + m][n] = __builtin_amdgcn_mfma_f32_16x16x32_bf16(a3[m], b2[n], acc[4 + m][n], 0, 0, 0);
    __builtin_amdgcn_s_setprio(0);
    if (more) { asm volatile("s_waitcnt vmcnt(2)" ::: "memory"); }
    __builtin_amdgcn_s_barrier();
    __builtin_amdgcn_sched_barrier(0);
  }

  // epilogue: bias + relu + bf16 store
  #pragma unroll
  for (int n = 0; n < 4; ++n) {
    int col = n0 + wn * 64 + n * 16 + (lane & 15);
    float bv = bias[col];
    #pragma unroll
    for (int m = 0; m < 8; ++m) {
      #pragma unroll
      for (int r = 0; r < 4; ++r) {
        int row = m0 + wm * 128 + m * 16 + (lane >> 4) * 4 + r;
        float v = fmaxf(acc[m][n][r] + bv, 0.f);
        C[(size_t)row * N + col] = f2bf(v);
      }
    }
  }
  #undef STAGE_A
  #undef STAGE_B
}

// ---------------- GEMM (bf16 A): m97 structure, 128x128 tile ----------------
__global__ __launch_bounds__(256) void gemm_glds(
    const __bf16* __restrict__ A, const __bf16* __restrict__ WT,
    const float* __restrict__ bias, __bf16* __restrict__ C,
    int N, int sA, int Kp)
{
  __shared__ __bf16 As[128][32];
  __shared__ __bf16 Bs[128][32];
  const int tid  = threadIdx.x;
  const int lane = tid & 63;
  const int wid  = tid >> 6;
  const int wr = wid >> 1, wc = wid & 1;
  const int m0 = blockIdx.x * 128, n0 = blockIdx.y * 128;

  const int srow = wid * 16 + (lane >> 2);
  const int scol = (lane & 3) * 8;
  const __bf16* Ag0 = A  + (size_t)(m0 + srow)      * sA + scol;
  const __bf16* Ag1 = A  + (size_t)(m0 + srow + 64) * sA + scol;
  const __bf16* Bg0 = WT + (size_t)(n0 + srow)      * Kp + scol;
  const __bf16* Bg1 = WT + (size_t)(n0 + srow + 64) * Kp + scol;
  __bf16* lA0 = &As[srow][scol];
  __bf16* lA1 = &As[srow + 64][scol];
  __bf16* lB0 = &Bs[srow][scol];
  __bf16* lB1 = &Bs[srow + 64][scol];

  f32x4 acc[4][4] = {};

  for (int k0 = 0; k0 < Kp; k0 += 32) {
    __syncthreads();
    GLDS16(Ag0 + k0, lA0);
    GLDS16(Ag1 + k0, lA1);
    GLDS16(Bg0 + k0, lB0);
    GLDS16(Bg1 + k0, lB1);
    __syncthreads();

    bf16x8 af[4], bfv[4];
    #pragma unroll
    for (int m = 0; m < 4; ++m)
      af[m] = *(const bf16x8*)&As[wr * 64 + m * 16 + (lane & 15)][(lane >> 4) * 8];
    #pragma unroll
    for (int n = 0; n < 4; ++n)
      bfv[n] = *(const bf16x8*)&Bs[wc * 64 + n * 16 + (lane & 15)][(lane >> 4) * 8];
    #pragma unroll
    for (int m = 0; m < 4; ++m)
      #pragma unroll
      for (int n = 0; n < 4; ++n)
        acc[m][n] = __builtin_amdgcn_mfma_f32_16x16x32_bf16(af[m], bfv[n], acc[m][n], 0, 0, 0);
  }

  #pragma unroll
  for (int m = 0; m < 4; ++m)
    #pragma unroll
    for (int n = 0; n < 4; ++n) {
      int col = n0 + wc * 64 + n * 16 + (lane & 15);
      float bv = bias[col];
      #pragma unroll
      for (int r = 0; r < 4; ++r) {
        int row = m0 + wr * 64 + m * 16 + (lane >> 4) * 4 + r;
        float v = fmaxf(acc[m][n][r] + bv, 0.f);
        C[(size_t)row * N + col] = f2bf(v);
      }
    }
}

// ---------------- GEMM (fp32 A, K<=32 single step): bottom layer 0 ----------------
__global__ __launch_bounds__(256) void gemm_f32a(
    const float* __restrict__ A, const __bf16* __restrict__ WT,
    const float* __restrict__ bias, __bf16* __restrict__ C,
    int N, int sA, int Kb, int Kp)
{
  __shared__ __bf16 As[128][40];
  __shared__ __bf16 Bs[128][40];
  const int tid  = threadIdx.x;
  const int lane = tid & 63;
  const int wid  = tid >> 6;
  const int wr = wid >> 1, wc = wid & 1;
  const int m0 = blockIdx.x * 128, n0 = blockIdx.y * 128;
  const int lrow = tid >> 2;
  const int lkk  = (tid & 3) * 8;

  f32x4 acc[4][4] = {};

  for (int k0 = 0; k0 < Kp; k0 += 32) {
    __syncthreads();
    #pragma unroll
    for (int it = 0; it < 2; ++it) {
      int row = lrow + it * 64;
      #pragma unroll
      for (int j = 0; j < 8; ++j) {
        int k = k0 + lkk + j;
        float v = (k < Kb) ? A[(size_t)(m0 + row) * sA + k] : 0.f;
        As[row][lkk + j] = f2bf(v);
      }
      *(bf16x8*)&Bs[row][lkk] = *(const bf16x8*)&WT[(size_t)(n0 + row) * Kp + k0 + lkk];
    }
    __syncthreads();

    bf16x8 af[4], bfv[4];
    #pragma unroll
    for (int m = 0; m < 4; ++m)
      af[m] = *(const bf16x8*)&As[wr * 64 + m * 16 + (lane & 15)][(lane >> 4) * 8];
    #pragma unroll
    for (int n = 0; n < 4; ++n)
      bfv[n] = *(const bf16x8*)&Bs[wc * 64 + n * 16 + (lane & 15)][(lane >> 4) * 8];
    #pragma unroll
    for (int m = 0; m < 4; ++m)
      #pragma unroll
      for (int n = 0; n < 4; ++n)
        acc[m][n] = __builtin_amdgcn_mfma_f32_16x16x32_bf16(af[m], bfv[n], acc[m][n], 0, 0, 0);
  }

  #pragma unroll
  for (int m = 0; m < 4; ++m)
    #pragma unroll
    for (int n = 0; n < 4; ++n) {
      int col = n0 + wc * 64 + n * 16 + (lane & 15);
      float bv = bias[col];
      #pragma unroll
      for (int r = 0; r < 4; ++r) {
        int row = m0 + wr * 64 + m * 16 + (lane >> 4) * 4 + r;
        float v = fmaxf(acc[m][n][r] + bv, 0.f);
        C[(size_t)row * N + col] = f2bf(v);
      }
    }
}

// ---------------- embedding gather + MFMA pairwise interaction ----------------
__global__ __launch_bounds__(256) void interact_mfma(
    const __bf16* __restrict__ bot, const int* __restrict__ xcat,
    const float* __restrict__ emb, __bf16* __restrict__ top_in)
{
  __shared__ __bf16 st[4][32][136];
  const int tid = threadIdx.x, lane = tid & 63, w = tid >> 6;
  const int s = blockIdx.x * 4 + w;

  {
    const __bf16* bp = bot + (size_t)s * 128 + lane * 2;
    st[w][0][lane * 2]     = bp[0];
    st[w][0][lane * 2 + 1] = bp[1];
  }
  const int* xr = xcat + (size_t)s * 26;
  #pragma unroll
  for (int r = 1; r < 27; ++r) {
    int ridx = xr[r - 1] & VOCAB_MASK;
    float2 v = *(const float2*)(emb + (size_t)ridx * 128 + lane * 2);
    st[w][r][lane * 2]     = f2bf(v.x);
    st[w][r][lane * 2 + 1] = f2bf(v.y);
  }
  #pragma unroll
  for (int r = 27; r < 32; ++r) {
    st[w][r][lane * 2]     = f2bf(0.f);
    st[w][r][lane * 2 + 1] = f2bf(0.f);
  }

  f32x4 a00 = {}, a01 = {}, a11 = {};
  #pragma unroll
  for (int k0 = 0; k0 < 4; ++k0) {
    bf16x8 fr0 = *(const bf16x8*)&st[w][(lane & 15)][k0 * 32 + (lane >> 4) * 8];
    bf16x8 fr1 = *(const bf16x8*)&st[w][16 + (lane & 15)][k0 * 32 + (lane >> 4) * 8];
    a00 = __builtin_amdgcn_mfma_f32_16x16x32_bf16(fr0, fr0, a00, 0, 0, 0);
    a01 = __builtin_amdgcn_mfma_f32_16x16x32_bf16(fr0, fr1, a01, 0, 0, 0);
    a11 = __builtin_amdgcn_mfma_f32_16x16x32_bf16(fr1, fr1, a11, 0, 0, 0);
  }

  __bf16* op = top_in + (size_t)s * 512;
  op[lane * 2]     = st[w][0][lane * 2];
  op[lane * 2 + 1] = st[w][0][lane * 2 + 1];
  if (lane < 6) op[506 + lane] = f2bf(0.f);

  const int jc = lane & 15, rb = (lane >> 4) * 4;
  #pragma unroll
  for (int r = 0; r < 4; ++r) {
    {
      int i = rb + r, j = jc;
      if (i <= j) op[128 + i * 27 - i * (i - 1) / 2 + (j - i)] = f2bf(a00[r]);
    }
    {
      int i = rb + r, j = 16 + jc;
      if (j <= 26) op[128 + i * 27 - i * (i - 1) / 2 + (j - i)] = f2bf(a01[r]);
    }
    {
      int i = 16 + rb + r, j = 16 + jc;
      if (i <= j && j <= 26) op[128 + i * 27 - i * (i - 1) / 2 + (j - i)] = f2bf(a11[r]);
    }
  }
}

// ---------------- final layer ----------------
__global__ __launch_bounds__(256) void final_kernel(
    const __bf16* __restrict__ t3, const float* __restrict__ w4,
    const float* __restrict__ b4, float* __restrict__ out)
{
  int row  = blockIdx.x * 4 + (threadIdx.x >> 6);
  int lane = threadIdx.x & 63;
  const __bf16* tr = &t3[(size_t)row * 256 + lane * 4];
  float acc = 0.f;
  #pragma unroll
  for (int j = 0; j < 4; ++j) acc += bf2f(tr[j]) * w4[lane * 4 + j];
  #pragma unroll
  for (int off = 32; off; off >>= 1) acc += __shfl_down(acc, off);
  if (lane == 0) out[row] = acc + b4[0];
}

extern "C" void kernel_launch(void* const* d_in, const int* in_sizes, int n_in,
                              void* d_out, int out_size, void* d_ws, size_t ws_size,
                              hipStream_t stream)
{
  const float* x_dense = (const float*)d_in[0];
  const int*   x_cat   = (const int*)d_in[1];
  const float* emb     = (const float*)d_in[2];
  const float* wb[3] = {(const float*)d_in[3], (const float*)d_in[5], (const float*)d_in[7]};
  const float* bb[3] = {(const float*)d_in[4], (const float*)d_in[6], (const float*)d_in[8]};
  const float* wt[5] = {(const float*)d_in[9],  (const float*)d_in[11], (const float*)d_in[13],
                        (const float*)d_in[15], (const float*)d_in[17]};
  const float* bt[5] = {(const float*)d_in[10], (const float*)d_in[12], (const float*)d_in[14],
                        (const float*)d_in[16], (const float*)d_in[18]};
  float* out = (float*)d_out;

  char* ws = (char*)d_ws;
  const size_t MB = 1ull << 20;
  __bf16* wt_b0 = (__bf16*)(ws + 0 * MB);   // 512x32
  __bf16* wt_b1 = (__bf16*)(ws + 1 * MB);   // 256x512
  __bf16* wt_b2 = (__bf16*)(ws + 2 * MB);   // 128x256
  __bf16* wt_t0 = (__bf16*)(ws + 3 * MB);   // 1024x512
  __bf16* wt_t1 = (__bf16*)(ws + 4 * MB);   // 1024x1024
  __bf16* wt_t2 = (__bf16*)(ws + 6 * MB);   // 512x1024
  __bf16* wt_t3 = (__bf16*)(ws + 7 * MB);   // 256x512
  __bf16* h2     = (__bf16*)(ws + 8 * MB);
  __bf16* top_in = (__bf16*)(ws + 12 * MB);
  __bf16* t2     = (__bf16*)(ws + 12 * MB);
  __bf16* h0     = (__bf16*)(ws + 28 * MB);
  __bf16* t1     = (__bf16*)(ws + 28 * MB);
  __bf16* t3     = (__bf16*)(ws + 28 * MB);
  __bf16* h1     = (__bf16*)(ws + 60 * MB);
  __bf16* t0     = (__bf16*)(ws + 60 * MB);

  // ---- fused weight prep (1 dispatch) ----
  TJobs js;
  const float* Ws[7] = {wb[0], wb[1], wb[2], wt[0], wt[1], wt[2], wt[3]};
  __bf16* WTs[7] = {wt_b0, wt_b1, wt_b2, wt_t0, wt_t1, wt_t2, wt_t3};
  int Ks[7]  = {13, 512, 256, 506, 1024, 1024, 512};
  int Ns[7]  = {512, 256, 128, 1024, 1024, 512, 256};
  int Kps[7] = {32, 512, 256, 512, 1024, 1024, 512};
  int off = 0;
  for (int i = 0; i < 7; ++i) {
    int tx = (Kps[i] + 63) / 64, ty = (Ns[i] + 63) / 64;
    js.j[i] = TJob{Ws[i], WTs[i], Ks[i], Ns[i], Kps[i], tx, off};
    off += tx * ty;
  }
  transpose_all<<<dim3(off), dim3(256), 0, stream>>>(js, 7);

  // ---- bottom MLP ----
  gemm_f32a<<<dim3(128, 4), dim3(256), 0, stream>>>(x_dense, wt_b0, bb[0], h0, 512, 13, 13, 32);
  gemm_glds<<<dim3(128, 2), dim3(256), 0, stream>>>(h0, wt_b1, bb[1], h1, 256, 512, 512);
  gemm_glds<<<dim3(128, 1), dim3(256), 0, stream>>>(h1, wt_b2, bb[2], h2, 128, 256, 256);

  // ---- embedding + interaction ----
  interact_mfma<<<dim3(BATCH / 4), dim3(256), 0, stream>>>(h2, x_cat, emb, top_in);

  // ---- top MLP: t0,t1 on the 256^2 phase-interleaved kernel ----
  gemm_8ph<<<dim3(256), dim3(512), 0, stream>>>(top_in, wt_t0, bt[0], t0, 1024, 512, 512, 64);
  gemm_8ph<<<dim3(256), dim3(512), 0, stream>>>(t0, wt_t1, bt[1], t1, 1024, 1024, 1024, 64);
  gemm_glds<<<dim3(128, 4), dim3(256), 0, stream>>>(t1, wt_t2, bt[2], t2, 512, 1024, 1024);
  gemm_glds<<<dim3(128, 2), dim3(256), 0, stream>>>(t2, wt_t3, bt[3], t3, 256, 512, 512);

  // ---- final dot ----
  final_kernel<<<dim3(BATCH / 4), dim3(256), 0, stream>>>(t3, wt[4], bt[4], out);
}

// Round 5
// 198.791 us; speedup vs baseline: 1.6362x; 1.0797x over previous
//
#include <hip/hip_runtime.h>
#include <cstdint>
#include <cstddef>

#define BATCH 16384
#define VOCAB_MASK (4194304 - 1)

typedef __attribute__((ext_vector_type(4))) float f32x4;
typedef __attribute__((ext_vector_type(8))) __bf16 bf16x8;

static_assert(sizeof(bf16x8) == 16, "bf16x8 must be 16 bytes");

static __device__ __forceinline__ __bf16 f2bf(float f) {
  union { float f; unsigned u; } in; in.f = f;
  unsigned r = in.u + 0x7FFF + ((in.u >> 16) & 1);
  union { unsigned short s; __bf16 b; } out; out.s = (unsigned short)(r >> 16);
  return out.b;
}
static __device__ __forceinline__ float bf2f(__bf16 b) {
  union { __bf16 b; unsigned short s; } in; in.b = b;
  union { unsigned u; float f; } out; out.u = ((unsigned)in.s) << 16;
  return out.f;
}

// async global->LDS, 16B per lane. LDS dest must be wave-uniform base + lane*16.
#define GLDS16(g, l) __builtin_amdgcn_global_load_lds( \
    (const __attribute__((address_space(1))) unsigned int*)(g), \
    (__attribute__((address_space(3))) unsigned int*)(l), 16, 0, 0)

// swizzle: XOR 16B-chunk index bits (involution within 1KB block)
static __device__ __forceinline__ unsigned swz16(unsigned b) {
  return b ^ ((((b >> 6) & 3u) ^ ((b >> 8) & 3u)) << 4);
}
// swizzled LDS fragment read: row r (64B rows), 16B byte-group cg, region base `base`
static __device__ __forceinline__ bf16x8 lds_frag(const char* smem, unsigned base,
                                                  unsigned r, unsigned cg) {
  unsigned b = r * 64u + cg;
  return *(const bf16x8*)(smem + base + swz16(b));
}

// ---------------- fused weight transpose + bf16 convert: WT[n][k] = W[k][n] ----------------
struct TJob { const float* W; __bf16* WT; int K, N, Kp, tx, off; };
struct TJobs { TJob j[7]; };

__global__ __launch_bounds__(256) void transpose_all(TJobs js, int njobs)
{
  __shared__ float tile[64][65];
  int b = blockIdx.x;
  int ji = 0;
  #pragma unroll
  for (int i = 1; i < 7; ++i) if (i < njobs && b >= js.j[i].off) ji = i;
  const TJob jb = js.j[ji];
  int lb = b - jb.off;
  int bx = lb % jb.tx, by = lb / jb.tx;
  const int kb = bx * 64, nb = by * 64;
  const int tx = threadIdx.x & 63, ty = threadIdx.x >> 6;
  #pragma unroll
  for (int i = 0; i < 64; i += 4) {
    int k = kb + ty + i, n = nb + tx;
    tile[ty + i][tx] = (k < jb.K && n < jb.N) ? jb.W[(size_t)k * jb.N + n] : 0.f;
  }
  __syncthreads();
  #pragma unroll
  for (int i = 0; i < 64; i += 4) {
    int n = nb + ty + i, k = kb + tx;
    if (n < jb.N && k < jb.Kp) jb.WT[(size_t)n * jb.Kp + k] = f2bf(tile[tx][ty + i]);
  }
}

// ---------------- fused bottom MLP: x(13) -> 512 -> 256 -> 128, all in LDS ----------------
// 512 blocks x 256 threads; 32 rows/block. Weights pre-transposed bf16 (wt_b0/b1/b2).
__global__ __launch_bounds__(256) void bottom_fused(
    const float* __restrict__ x,
    const __bf16* __restrict__ w0t, const float* __restrict__ b0,
    const __bf16* __restrict__ w1t, const float* __restrict__ b1,
    const __bf16* __restrict__ w2t, const float* __restrict__ b2,
    __bf16* __restrict__ h2out)
{
  __shared__ __bf16 h0s[32][520];   // stride 130 words % 32 = 2  -> <=2-way (free)
  __shared__ __bf16 h1s[32][264];   // stride 132 words % 32 = 4  -> <=2-way
  __shared__ __bf16 As[32][40];
  __shared__ __bf16 Bs[256][32];    // GLDS dest: linear [row][32]
  const int tid = threadIdx.x, lane = tid & 63, w = tid >> 6;
  const int r0 = blockIdx.x * 32;
  const int srow_b = lane >> 2;           // 0..15
  const int scol_b = (lane & 3) * 8;      // bf16 offset (16B per lane)
  const unsigned rA = lane & 15, cgw = (lane >> 4) * 8;  // frag row / bf16 col group

  // stage A: x[r0..r0+31][0..12] -> bf16, zero-pad to col 40
  for (int idx = tid; idx < 32 * 40; idx += 256) {
    int row = idx / 40, k = idx - row * 40;
    float v = (k < 13) ? x[(size_t)(r0 + row) * 13 + k] : 0.f;
    As[row][k] = f2bf(v);
  }

  // ---- layer 0: h0 = relu(A @ W0 + b0), N=512 in two 256-col passes, K=32 ----
  #pragma unroll
  for (int p = 0; p < 2; ++p) {
    __syncthreads();   // As ready / prev pass b-frag reads done
    #pragma unroll
    for (int c = 0; c < 4; ++c) {
      int row = w * 64 + c * 16 + srow_b;
      GLDS16(w0t + (size_t)(p * 256 + row) * 32 + scol_b, &Bs[row][scol_b]);
    }
    __syncthreads();   // Bs ready
    bf16x8 a[2], bv[4];
    #pragma unroll
    for (int m = 0; m < 2; ++m) a[m] = *(const bf16x8*)&As[rA + m * 16][cgw];
    #pragma unroll
    for (int n = 0; n < 4; ++n) bv[n] = *(const bf16x8*)&Bs[w * 64 + n * 16 + rA][cgw];
    f32x4 acc[2][4] = {};
    #pragma unroll
    for (int m = 0; m < 2; ++m)
      #pragma unroll
      for (int n = 0; n < 4; ++n)
        acc[m][n] = __builtin_amdgcn_mfma_f32_16x16x32_bf16(a[m], bv[n], acc[m][n], 0, 0, 0);
    #pragma unroll
    for (int m = 0; m < 2; ++m)
      #pragma unroll
      for (int n = 0; n < 4; ++n) {
        int col = p * 256 + w * 64 + n * 16 + (int)rA;
        float bb = b0[col];
        #pragma unroll
        for (int r = 0; r < 4; ++r) {
          int row = m * 16 + (lane >> 4) * 4 + r;
          h0s[row][col] = f2bf(fmaxf(acc[m][n][r] + bb, 0.f));
        }
      }
  }

  // ---- layer 1: h1 = relu(h0 @ W1 + b1), N=256, K=512 ----
  f32x4 acc1[2][4] = {};
  for (int k0 = 0; k0 < 512; k0 += 32) {
    __syncthreads();   // h0s writes done (first iter) / prev b-reads done
    #pragma unroll
    for (int c = 0; c < 4; ++c) {
      int row = w * 64 + c * 16 + srow_b;
      GLDS16(w1t + (size_t)row * 512 + k0 + scol_b, &Bs[row][scol_b]);
    }
    __syncthreads();
    bf16x8 a[2], bv[4];
    #pragma unroll
    for (int m = 0; m < 2; ++m) a[m] = *(const bf16x8*)&h0s[rA + m * 16][k0 + cgw];
    #pragma unroll
    for (int n = 0; n < 4; ++n) bv[n] = *(const bf16x8*)&Bs[w * 64 + n * 16 + rA][cgw];
    #pragma unroll
    for (int m = 0; m < 2; ++m)
      #pragma unroll
      for (int n = 0; n < 4; ++n)
        acc1[m][n] = __builtin_amdgcn_mfma_f32_16x16x32_bf16(a[m], bv[n], acc1[m][n], 0, 0, 0);
  }
  #pragma unroll
  for (int m = 0; m < 2; ++m)
    #pragma unroll
    for (int n = 0; n < 4; ++n) {
      int col = w * 64 + n * 16 + (int)rA;
      float bb = b1[col];
      #pragma unroll
      for (int r = 0; r < 4; ++r) {
        int row = m * 16 + (lane >> 4) * 4 + r;
        h1s[row][col] = f2bf(fmaxf(acc1[m][n][r] + bb, 0.f));
      }
    }

  // ---- layer 2: h2 = relu(h1 @ W2 + b2), N=128, K=256 ----
  f32x4 acc2[2][2] = {};
  for (int k0 = 0; k0 < 256; k0 += 32) {
    __syncthreads();
    #pragma unroll
    for (int c = 0; c < 2; ++c) {
      int row = w * 32 + c * 16 + srow_b;
      GLDS16(w2t + (size_t)row * 256 + k0 + scol_b, &Bs[row][scol_b]);
    }
    __syncthreads();
    bf16x8 a[2], bv[2];
    #pragma unroll
    for (int m = 0; m < 2; ++m) a[m] = *(const bf16x8*)&h1s[rA + m * 16][k0 + cgw];
    #pragma unroll
    for (int n = 0; n < 2; ++n) bv[n] = *(const bf16x8*)&Bs[w * 32 + n * 16 + rA][cgw];
    #pragma unroll
    for (int m = 0; m < 2; ++m)
      #pragma unroll
      for (int n = 0; n < 2; ++n)
        acc2[m][n] = __builtin_amdgcn_mfma_f32_16x16x32_bf16(a[m], bv[n], acc2[m][n], 0, 0, 0);
  }
  #pragma unroll
  for (int m = 0; m < 2; ++m)
    #pragma unroll
    for (int n = 0; n < 2; ++n) {
      int col = w * 32 + n * 16 + (int)rA;
      float bb = b2[col];
      #pragma unroll
      for (int r = 0; r < 4; ++r) {
        int row = m * 16 + (lane >> 4) * 4 + r;
        h2out[(size_t)(r0 + row) * 128 + col] = f2bf(fmaxf(acc2[m][n][r] + bb, 0.f));
      }
    }
}

// ---------------- 256x256 phase-interleaved GEMM (T1+T2+T3+T4+T5), BK=32 ----------------
__global__ __launch_bounds__(512, 2) void gemm_8ph(
    const __bf16* __restrict__ A, const __bf16* __restrict__ WT,
    const float* __restrict__ bias, __bf16* __restrict__ C,
    int N, int sA, int K, int gm)
{
  __shared__ __align__(16) char smem[65536];
  const int tid = threadIdx.x, lane = tid & 63, w = tid >> 6;
  const int wm = w >> 2, wn = w & 3;

  int nb = gridDim.x;
  int id = blockIdx.x;
  int swz = ((nb & 7) == 0) ? ((id & 7) * (nb >> 3) + (id >> 3)) : id;
  const int m0 = (swz % gm) * 256, n0 = (swz / gm) * 256;

  unsigned Ld[2]; const __bf16* sAp[2]; const __bf16* sBp[2];
  #pragma unroll
  for (int h = 0; h < 2; ++h) {
    unsigned L = h * 8192u + (unsigned)w * 1024u + (unsigned)lane * 16u;
    unsigned Ls = swz16(L);
    Ld[h] = L;
    int srow = Ls >> 6, scb = Ls & 63;
    sAp[h] = A  + (size_t)(m0 + srow) * sA + (scb >> 1);
    sBp[h] = WT + (size_t)(n0 + srow) * K  + (scb >> 1);
  }

  #define STAGE_A(kt, p) { GLDS16(sAp[0] + (kt)*32, smem + (p)*32768 + Ld[0]); \
                           GLDS16(sAp[1] + (kt)*32, smem + (p)*32768 + Ld[1]); }
  #define STAGE_B(kt, p) { GLDS16(sBp[0] + (kt)*32, smem + (p)*32768 + 16384 + Ld[0]); \
                           GLDS16(sBp[1] + (kt)*32, smem + (p)*32768 + 16384 + Ld[1]); }

  const unsigned cg = (lane >> 4) * 16u;
  const unsigned rA = (lane & 15);

  f32x4 acc[8][4] = {};
  const int iters = (K >> 5) >> 1;

  STAGE_B(0, 0); STAGE_A(0, 0); STAGE_B(1, 1);
  asm volatile("s_waitcnt vmcnt(2)" ::: "memory");
  __builtin_amdgcn_s_barrier();
  __builtin_amdgcn_sched_barrier(0);

  for (int i = 0; i < iters; ++i) {
    const int t = 2 * i;
    const bool more = (i + 1 < iters);

    bf16x8 a0[4], b0[4];
    #pragma unroll
    for (int m = 0; m < 4; ++m) a0[m] = lds_frag(smem, 0, wm * 128 + m * 16 + rA, cg);
    #pragma unroll
    for (int n = 0; n < 4; ++n) b0[n] = lds_frag(smem, 16384, wn * 64 + n * 16 + rA, cg);
    STAGE_A(t + 1, 1);
    __builtin_amdgcn_s_barrier();
    asm volatile("s_waitcnt lgkmcnt(0)" ::: "memory");
    __builtin_amdgcn_sched_barrier(0);
    __builtin_amdgcn_s_setprio(1);
    #pragma unroll
    for (int m = 0; m < 4; ++m)
      #pragma unroll
      for (int n = 0; n < 4; ++n)
        acc[m][n] = __builtin_amdgcn_mfma_f32_16x16x32_bf16(a0[m], b0[n], acc[m][n], 0, 0, 0);
    __builtin_amdgcn_s_setprio(0);
    __builtin_amdgcn_s_barrier();
    __builtin_amdgcn_sched_barrier(0);

    bf16x8 a1[4];
    #pragma unroll
    for (int m = 0; m < 4; ++m) a1[m] = lds_frag(smem, 0, wm * 128 + 64 + m * 16 + rA, cg);
    if (more) STAGE_B(t + 2, 0);
    __builtin_amdgcn_s_barrier();
    asm volatile("s_waitcnt lgkmcnt(0)" ::: "memory");
    __builtin_amdgcn_sched_barrier(0);
    __builtin_amdgcn_s_setprio(1);
    #pragma unroll
    for (int m = 0; m < 4; ++m)
      #pragma unroll
      for (int n = 0; n < 4; ++n)
        acc[4 + m][n] = __builtin_amdgcn_mfma_f32_16x16x32_bf16(a1[m], b0[n], acc[4 + m][n], 0, 0, 0);
    __builtin_amdgcn_s_setprio(0);
    if (more) { asm volatile("s_waitcnt vmcnt(2)" ::: "memory"); }
    else      { asm volatile("s_waitcnt vmcnt(0)" ::: "memory"); }
    __builtin_amdgcn_s_barrier();
    __builtin_amdgcn_sched_barrier(0);

    bf16x8 a2[4], b2[4];
    #pragma unroll
    for (int m = 0; m < 4; ++m) a2[m] = lds_frag(smem, 32768, wm * 128 + m * 16 + rA, cg);
    #pragma unroll
    for (int n = 0; n < 4; ++n) b2[n] = lds_frag(smem, 32768 + 16384, wn * 64 + n * 16 + rA, cg);
    if (more) STAGE_A(t + 2, 0);
    __builtin_amdgcn_s_barrier();
    asm volatile("s_waitcnt lgkmcnt(0)" ::: "memory");
    __builtin_amdgcn_sched_barrier(0);
    __builtin_amdgcn_s_setprio(1);
    #pragma unroll
    for (int m = 0; m < 4; ++m)
      #pragma unroll
      for (int n = 0; n < 4; ++n)
        acc[m][n] = __builtin_amdgcn_mfma_f32_16x16x32_bf16(a2[m], b2[n], acc[m][n], 0, 0, 0);
    __builtin_amdgcn_s_setprio(0);
    __builtin_amdgcn_s_barrier();
    __builtin_amdgcn_sched_barrier(0);

    bf16x8 a3[4];
    #pragma unroll
    for (int m = 0; m < 4; ++m) a3[m] = lds_frag(smem, 32768, wm * 128 + 64 + m * 16 + rA, cg);
    if (more) STAGE_B(t + 3, 1);
    __builtin_amdgcn_s_barrier();
    asm volatile("s_waitcnt lgkmcnt(0)" ::: "memory");
    __builtin_amdgcn_sched_barrier(0);
    __builtin_amdgcn_s_setprio(1);
    #pragma unroll
    for (int m = 0; m < 4; ++m)
      #pragma unroll
      for (int n = 0; n < 4; ++n)
        acc[4 + m][n] = __builtin_amdgcn_mfma_f32_16x16x32_bf16(a3[m], b2[n], acc[4 + m][n], 0, 0, 0);
    __builtin_amdgcn_s_setprio(0);
    if (more) { asm volatile("s_waitcnt vmcnt(2)" ::: "memory"); }
    __builtin_amdgcn_s_barrier();
    __builtin_amdgcn_sched_barrier(0);
  }

  #pragma unroll
  for (int n = 0; n < 4; ++n) {
    int col = n0 + wn * 64 + n * 16 + (lane & 15);
    float bv = bias[col];
    #pragma unroll
    for (int m = 0; m < 8; ++m) {
      #pragma unroll
      for (int r = 0; r < 4; ++r) {
        int row = m0 + wm * 128 + m * 16 + (lane >> 4) * 4 + r;
        float v = fmaxf(acc[m][n][r] + bv, 0.f);
        C[(size_t)row * N + col] = f2bf(v);
      }
    }
  }
  #undef STAGE_A
  #undef STAGE_B
}

// ---------------- 256x128-tile phase-interleaved GEMM (for N%256 != grid-friendly) ----------
// wave grid 4M x 2N, wave tile 64x64. LDS 48KB: buf p @ p*24576: A[256][32], B[128][32] @ +16384.
__global__ __launch_bounds__(512, 2) void gemm_8ph_n128(
    const __bf16* __restrict__ A, const __bf16* __restrict__ WT,
    const float* __restrict__ bias, __bf16* __restrict__ C,
    int N, int sA, int K, int gm)
{
  __shared__ __align__(16) char smem[49152];
  const int tid = threadIdx.x, lane = tid & 63, w = tid >> 6;
  const int wm = w >> 1, wn = w & 1;

  int nb = gridDim.x;
  int id = blockIdx.x;
  int swz = ((nb & 7) == 0) ? ((id & 7) * (nb >> 3) + (id >> 3)) : id;
  const int m0 = (swz % gm) * 256, n0 = (swz / gm) * 128;

  unsigned Ld[2]; const __bf16* sAp[2]; const __bf16* sBp0;
  #pragma unroll
  for (int h = 0; h < 2; ++h) {
    unsigned L = h * 8192u + (unsigned)w * 1024u + (unsigned)lane * 16u;
    unsigned Ls = swz16(L);
    Ld[h] = L;
    int srow = Ls >> 6, scb = Ls & 63;
    sAp[h] = A + (size_t)(m0 + srow) * sA + (scb >> 1);
  }
  {
    unsigned L = (unsigned)w * 1024u + (unsigned)lane * 16u;   // 8KB B region
    unsigned Ls = swz16(L);
    int srow = Ls >> 6, scb = Ls & 63;
    sBp0 = WT + (size_t)(n0 + srow) * K + (scb >> 1);
  }

  #define STAGE_A2(kt, p) { GLDS16(sAp[0] + (kt)*32, smem + (p)*24576 + Ld[0]); \
                            GLDS16(sAp[1] + (kt)*32, smem + (p)*24576 + Ld[1]); }
  #define STAGE_B1(kt, p) { GLDS16(sBp0 + (kt)*32, smem + (p)*24576 + 16384 + Ld[0]); }

  const unsigned cg = (lane >> 4) * 16u;
  const unsigned rA = (lane & 15);

  f32x4 acc[4][4] = {};
  const int iters = (K >> 5) >> 1;

  // prologue: B0[1], A0[2], B1[1]; guard t0 -> vmcnt(1)
  STAGE_B1(0, 0); STAGE_A2(0, 0); STAGE_B1(1, 1);
  asm volatile("s_waitcnt vmcnt(1)" ::: "memory");
  __builtin_amdgcn_s_barrier();
  __builtin_amdgcn_sched_barrier(0);

  for (int i = 0; i < iters; ++i) {
    const int t = 2 * i;
    const bool more = (i + 1 < iters);

    // ph0: tile t (buf0) m-frags 0,1 ; stage A(t+1)->buf1
    bf16x8 a0[2], b0[4];
    #pragma unroll
    for (int m = 0; m < 2; ++m) a0[m] = lds_frag(smem, 0, wm * 64 + m * 16 + rA, cg);
    #pragma unroll
    for (int n = 0; n < 4; ++n) b0[n] = lds_frag(smem, 16384, wn * 64 + n * 16 + rA, cg);
    STAGE_A2(t + 1, 1);
    __builtin_amdgcn_s_barrier();
    asm volatile("s_waitcnt lgkmcnt(0)" ::: "memory");
    __builtin_amdgcn_sched_barrier(0);
    __builtin_amdgcn_s_setprio(1);
    #pragma unroll
    for (int m = 0; m < 2; ++m)
      #pragma unroll
      for (int n = 0; n < 4; ++n)
        acc[m][n] = __builtin_amdgcn_mfma_f32_16x16x32_bf16(a0[m], b0[n], acc[m][n], 0, 0, 0);
    __builtin_amdgcn_s_setprio(0);
    __builtin_amdgcn_s_barrier();
    __builtin_amdgcn_sched_barrier(0);

    // ph1: tile t m-frags 2,3 ; stage B(t+2)->buf0 ; guard tile t+1
    bf16x8 a1[2];
    #pragma unroll
    for (int m = 0; m < 2; ++m) a1[m] = lds_frag(smem, 0, wm * 64 + 32 + m * 16 + rA, cg);
    if (more) STAGE_B1(t + 2, 0);
    __builtin_amdgcn_s_barrier();
    asm volatile("s_waitcnt lgkmcnt(0)" ::: "memory");
    __builtin_amdgcn_sched_barrier(0);
    __builtin_amdgcn_s_setprio(1);
    #pragma unroll
    for (int m = 0; m < 2; ++m)
      #pragma unroll
      for (int n = 0; n < 4; ++n)
        acc[2 + m][n] = __builtin_amdgcn_mfma_f32_16x16x32_bf16(a1[m], b0[n], acc[2 + m][n], 0, 0, 0);
    __builtin_amdgcn_s_setprio(0);
    if (more) { asm volatile("s_waitcnt vmcnt(1)" ::: "memory"); }
    else      { asm volatile("s_waitcnt vmcnt(0)" ::: "memory"); }
    __builtin_amdgcn_s_barrier();
    __builtin_amdgcn_sched_barrier(0);

    // ph2: tile t+1 (buf1) m-frags 0,1 ; stage A(t+2)->buf0
    bf16x8 a2[2], b2[4];
    #pragma unroll
    for (int m = 0; m < 2; ++m) a2[m] = lds_frag(smem, 24576, wm * 64 + m * 16 + rA, cg);
    #pragma unroll
    for (int n = 0; n < 4; ++n) b2[n] = lds_frag(smem, 24576 + 16384, wn * 64 + n * 16 + rA, cg);
    if (more) STAGE_A2(t + 2, 0);
    __builtin_amdgcn_s_barrier();
    asm volatile("s_waitcnt lgkmcnt(0)" ::: "memory");
    __builtin_amdgcn_sched_barrier(0);
    __builtin_amdgcn_s_setprio(1);
    #pragma unroll
    for (int m = 0; m < 2; ++m)
      #pragma unroll
      for (int n = 0; n < 4; ++n)
        acc[m][n] = __builtin_amdgcn_mfma_f32_16x16x32_bf16(a2[m], b2[n], acc[m][n], 0, 0, 0);
    __builtin_amdgcn_s_setprio(0);
    __builtin_amdgcn_s_barrier();
    __builtin_amdgcn_sched_barrier(0);

    // ph3: tile t+1 m-frags 2,3 ; stage B(t+3)->buf1 ; guard tile t+2
    bf16x8 a3[2];
    #pragma unroll
    for (int m = 0; m < 2; ++m) a3[m] = lds_frag(smem, 24576, wm * 64 + 32 + m * 16 + rA, cg);
    if (more) STAGE_B1(t + 3, 1);
    __builtin_amdgcn_s_barrier();
    asm volatile("s_waitcnt lgkmcnt(0)" ::: "memory");
    __builtin_amdgcn_sched_barrier(0);
    __builtin_amdgcn_s_setprio(1);
    #pragma unroll
    for (int m = 0; m < 2; ++m)
      #pragma unroll
      for (int n = 0; n < 4; ++n)
        acc[2 + m][n] = __builtin_amdgcn_mfma_f32_16x16x32_bf16(a3[m], b2[n], acc[2 + m][n], 0, 0, 0);
    __builtin_amdgcn_s_setprio(0);
    if (more) { asm volatile("s_waitcnt vmcnt(1)" ::: "memory"); }
    __builtin_amdgcn_s_barrier();
    __builtin_amdgcn_sched_barrier(0);
  }

  #pragma unroll
  for (int n = 0; n < 4; ++n) {
    int col = n0 + wn * 64 + n * 16 + (lane & 15);
    float bv = bias[col];
    #pragma unroll
    for (int m = 0; m < 4; ++m) {
      #pragma unroll
      for (int r = 0; r < 4; ++r) {
        int row = m0 + wm * 64 + m * 16 + (lane >> 4) * 4 + r;
        float v = fmaxf(acc[m][n][r] + bv, 0.f);
        C[(size_t)row * N + col] = f2bf(v);
      }
    }
  }
  #undef STAGE_A2
  #undef STAGE_B1
}

// ---------------- GEMM (bf16 A): m97 structure, 128x128 tile ----------------
__global__ __launch_bounds__(256) void gemm_glds(
    const __bf16* __restrict__ A, const __bf16* __restrict__ WT,
    const float* __restrict__ bias, __bf16* __restrict__ C,
    int N, int sA, int Kp)
{
  __shared__ __bf16 As[128][32];
  __shared__ __bf16 Bs[128][32];
  const int tid  = threadIdx.x;
  const int lane = tid & 63;
  const int wid  = tid >> 6;
  const int wr = wid >> 1, wc = wid & 1;
  const int m0 = blockIdx.x * 128, n0 = blockIdx.y * 128;

  const int srow = wid * 16 + (lane >> 2);
  const int scol = (lane & 3) * 8;
  const __bf16* Ag0 = A  + (size_t)(m0 + srow)      * sA + scol;
  const __bf16* Ag1 = A  + (size_t)(m0 + srow + 64) * sA + scol;
  const __bf16* Bg0 = WT + (size_t)(n0 + srow)      * Kp + scol;
  const __bf16* Bg1 = WT + (size_t)(n0 + srow + 64) * Kp + scol;
  __bf16* lA0 = &As[srow][scol];
  __bf16* lA1 = &As[srow + 64][scol];
  __bf16* lB0 = &Bs[srow][scol];
  __bf16* lB1 = &Bs[srow + 64][scol];

  f32x4 acc[4][4] = {};

  for (int k0 = 0; k0 < Kp; k0 += 32) {
    __syncthreads();
    GLDS16(Ag0 + k0, lA0);
    GLDS16(Ag1 + k0, lA1);
    GLDS16(Bg0 + k0, lB0);
    GLDS16(Bg1 + k0, lB1);
    __syncthreads();

    bf16x8 af[4], bfv[4];
    #pragma unroll
    for (int m = 0; m < 4; ++m)
      af[m] = *(const bf16x8*)&As[wr * 64 + m * 16 + (lane & 15)][(lane >> 4) * 8];
    #pragma unroll
    for (int n = 0; n < 4; ++n)
      bfv[n] = *(const bf16x8*)&Bs[wc * 64 + n * 16 + (lane & 15)][(lane >> 4) * 8];
    #pragma unroll
    for (int m = 0; m < 4; ++m)
      #pragma unroll
      for (int n = 0; n < 4; ++n)
        acc[m][n] = __builtin_amdgcn_mfma_f32_16x16x32_bf16(af[m], bfv[n], acc[m][n], 0, 0, 0);
  }

  #pragma unroll
  for (int m = 0; m < 4; ++m)
    #pragma unroll
    for (int n = 0; n < 4; ++n) {
      int col = n0 + wc * 64 + n * 16 + (lane & 15);
      float bv = bias[col];
      #pragma unroll
      for (int r = 0; r < 4; ++r) {
        int row = m0 + wr * 64 + m * 16 + (lane >> 4) * 4 + r;
        float v = fmaxf(acc[m][n][r] + bv, 0.f);
        C[(size_t)row * N + col] = f2bf(v);
      }
    }
}

// ---------------- embedding gather + MFMA pairwise interaction ----------------
__global__ __launch_bounds__(256) void interact_mfma(
    const __bf16* __restrict__ bot, const int* __restrict__ xcat,
    const float* __restrict__ emb, __bf16* __restrict__ top_in)
{
  __shared__ __bf16 st[4][32][136];
  const int tid = threadIdx.x, lane = tid & 63, w = tid >> 6;
  const int s = blockIdx.x * 4 + w;

  {
    const __bf16* bp = bot + (size_t)s * 128 + lane * 2;
    st[w][0][lane * 2]     = bp[0];
    st[w][0][lane * 2 + 1] = bp[1];
  }
  const int* xr = xcat + (size_t)s * 26;
  #pragma unroll
  for (int r = 1; r < 27; ++r) {
    int ridx = xr[r - 1] & VOCAB_MASK;
    float2 v = *(const float2*)(emb + (size_t)ridx * 128 + lane * 2);
    st[w][r][lane * 2]     = f2bf(v.x);
    st[w][r][lane * 2 + 1] = f2bf(v.y);
  }
  #pragma unroll
  for (int r = 27; r < 32; ++r) {
    st[w][r][lane * 2]     = f2bf(0.f);
    st[w][r][lane * 2 + 1] = f2bf(0.f);
  }

  f32x4 a00 = {}, a01 = {}, a11 = {};
  #pragma unroll
  for (int k0 = 0; k0 < 4; ++k0) {
    bf16x8 fr0 = *(const bf16x8*)&st[w][(lane & 15)][k0 * 32 + (lane >> 4) * 8];
    bf16x8 fr1 = *(const bf16x8*)&st[w][16 + (lane & 15)][k0 * 32 + (lane >> 4) * 8];
    a00 = __builtin_amdgcn_mfma_f32_16x16x32_bf16(fr0, fr0, a00, 0, 0, 0);
    a01 = __builtin_amdgcn_mfma_f32_16x16x32_bf16(fr0, fr1, a01, 0, 0, 0);
    a11 = __builtin_amdgcn_mfma_f32_16x16x32_bf16(fr1, fr1, a11, 0, 0, 0);
  }

  __bf16* op = top_in + (size_t)s * 512;
  op[lane * 2]     = st[w][0][lane * 2];
  op[lane * 2 + 1] = st[w][0][lane * 2 + 1];
  if (lane < 6) op[506 + lane] = f2bf(0.f);

  const int jc = lane & 15, rb = (lane >> 4) * 4;
  #pragma unroll
  for (int r = 0; r < 4; ++r) {
    {
      int i = rb + r, j = jc;
      if (i <= j) op[128 + i * 27 - i * (i - 1) / 2 + (j - i)] = f2bf(a00[r]);
    }
    {
      int i = rb + r, j = 16 + jc;
      if (j <= 26) op[128 + i * 27 - i * (i - 1) / 2 + (j - i)] = f2bf(a01[r]);
    }
    {
      int i = 16 + rb + r, j = 16 + jc;
      if (i <= j && j <= 26) op[128 + i * 27 - i * (i - 1) / 2 + (j - i)] = f2bf(a11[r]);
    }
  }
}

// ---------------- final layer ----------------
__global__ __launch_bounds__(256) void final_kernel(
    const __bf16* __restrict__ t3, const float* __restrict__ w4,
    const float* __restrict__ b4, float* __restrict__ out)
{
  int row  = blockIdx.x * 4 + (threadIdx.x >> 6);
  int lane = threadIdx.x & 63;
  const __bf16* tr = &t3[(size_t)row * 256 + lane * 4];
  float acc = 0.f;
  #pragma unroll
  for (int j = 0; j < 4; ++j) acc += bf2f(tr[j]) * w4[lane * 4 + j];
  #pragma unroll
  for (int off = 32; off; off >>= 1) acc += __shfl_down(acc, off);
  if (lane == 0) out[row] = acc + b4[0];
}

extern "C" void kernel_launch(void* const* d_in, const int* in_sizes, int n_in,
                              void* d_out, int out_size, void* d_ws, size_t ws_size,
                              hipStream_t stream)
{
  const float* x_dense = (const float*)d_in[0];
  const int*   x_cat   = (const int*)d_in[1];
  const float* emb     = (const float*)d_in[2];
  const float* wb[3] = {(const float*)d_in[3], (const float*)d_in[5], (const float*)d_in[7]};
  const float* bb[3] = {(const float*)d_in[4], (const float*)d_in[6], (const float*)d_in[8]};
  const float* wt[5] = {(const float*)d_in[9],  (const float*)d_in[11], (const float*)d_in[13],
                        (const float*)d_in[15], (const float*)d_in[17]};
  const float* bt[5] = {(const float*)d_in[10], (const float*)d_in[12], (const float*)d_in[14],
                        (const float*)d_in[16], (const float*)d_in[18]};
  float* out = (float*)d_out;

  char* ws = (char*)d_ws;
  const size_t MB = 1ull << 20;
  __bf16* wt_b0 = (__bf16*)(ws + 0 * MB);   // 512x32
  __bf16* wt_b1 = (__bf16*)(ws + 1 * MB);   // 256x512
  __bf16* wt_b2 = (__bf16*)(ws + 2 * MB);   // 128x256
  __bf16* wt_t0 = (__bf16*)(ws + 3 * MB);   // 1024x512
  __bf16* wt_t1 = (__bf16*)(ws + 4 * MB);   // 1024x1024
  __bf16* wt_t2 = (__bf16*)(ws + 6 * MB);   // 512x1024
  __bf16* wt_t3 = (__bf16*)(ws + 7 * MB);   // 256x512
  __bf16* h2     = (__bf16*)(ws + 8 * MB);   // 16384x128 = 4MB
  __bf16* top_in = (__bf16*)(ws + 12 * MB);  // 16MB (region C)
  __bf16* t2     = (__bf16*)(ws + 12 * MB);  // (region C, after top_in dead)
  __bf16* t1     = (__bf16*)(ws + 28 * MB);  // 32MB (region A)
  __bf16* t3     = (__bf16*)(ws + 28 * MB);  // (region A, after t1 dead)
  __bf16* t0     = (__bf16*)(ws + 60 * MB);  // 32MB (region B)

  // ---- fused weight prep (1 dispatch) ----
  TJobs js;
  const float* Ws[7] = {wb[0], wb[1], wb[2], wt[0], wt[1], wt[2], wt[3]};
  __bf16* WTs[7] = {wt_b0, wt_b1, wt_b2, wt_t0, wt_t1, wt_t2, wt_t3};
  int Ks[7]  = {13, 512, 256, 506, 1024, 1024, 512};
  int Ns[7]  = {512, 256, 128, 1024, 1024, 512, 256};
  int Kps[7] = {32, 512, 256, 512, 1024, 1024, 512};
  int off = 0;
  for (int i = 0; i < 7; ++i) {
    int tx = (Kps[i] + 63) / 64, ty = (Ns[i] + 63) / 64;
    js.j[i] = TJob{Ws[i], WTs[i], Ks[i], Ns[i], Kps[i], tx, off};
    off += tx * ty;
  }
  transpose_all<<<dim3(off), dim3(256), 0, stream>>>(js, 7);

  // ---- fused bottom MLP (1 dispatch) ----
  bottom_fused<<<dim3(BATCH / 32), dim3(256), 0, stream>>>(
      x_dense, wt_b0, bb[0], wt_b1, bb[1], wt_b2, bb[2], h2);

  // ---- embedding + interaction ----
  interact_mfma<<<dim3(BATCH / 4), dim3(256), 0, stream>>>(h2, x_cat, emb, top_in);

  // ---- top MLP ----
  gemm_8ph<<<dim3(256), dim3(512), 0, stream>>>(top_in, wt_t0, bt[0], t0, 1024, 512, 512, 64);
  gemm_8ph<<<dim3(256), dim3(512), 0, stream>>>(t0, wt_t1, bt[1], t1, 1024, 1024, 1024, 64);
  gemm_8ph_n128<<<dim3(256), dim3(512), 0, stream>>>(t1, wt_t2, bt[2], t2, 512, 1024, 1024, 64);
  gemm_glds<<<dim3(128, 2), dim3(256), 0, stream>>>(t2, wt_t3, bt[3], t3, 256, 512, 512);

  // ---- final dot ----
  final_kernel<<<dim3(BATCH / 4), dim3(256), 0, stream>>>(t3, wt[4], bt[4], out);
}

// Round 6
// 197.398 us; speedup vs baseline: 1.6477x; 1.0071x over previous
//
#include <hip/hip_runtime.h>
#include <cstdint>
#include <cstddef>

#define BATCH 16384
#define VOCAB_MASK (4194304 - 1)

typedef __attribute__((ext_vector_type(4))) float f32x4;
typedef __attribute__((ext_vector_type(8))) __bf16 bf16x8;
typedef __attribute__((ext_vector_type(4))) __bf16 bf16x4;

static_assert(sizeof(bf16x8) == 16, "bf16x8 must be 16 bytes");

static __device__ __forceinline__ __bf16 f2bf(float f) {
  union { float f; unsigned u; } in; in.f = f;
  unsigned r = in.u + 0x7FFF + ((in.u >> 16) & 1);
  union { unsigned short s; __bf16 b; } out; out.s = (unsigned short)(r >> 16);
  return out.b;
}
static __device__ __forceinline__ float bf2f(__bf16 b) {
  union { __bf16 b; unsigned short s; } in; in.b = b;
  union { unsigned u; float f; } out; out.u = ((unsigned)in.s) << 16;
  return out.f;
}

// async global->LDS, 16B per lane. LDS dest must be wave-uniform base + lane*16.
#define GLDS16(g, l) __builtin_amdgcn_global_load_lds( \
    (const __attribute__((address_space(1))) unsigned int*)(g), \
    (__attribute__((address_space(3))) unsigned int*)(l), 16, 0, 0)

// swizzle: XOR 16B-chunk index bits (involution within 1KB block)
static __device__ __forceinline__ unsigned swz16(unsigned b) {
  return b ^ ((((b >> 6) & 3u) ^ ((b >> 8) & 3u)) << 4);
}
static __device__ __forceinline__ bf16x8 lds_frag(const char* smem, unsigned base,
                                                  unsigned r, unsigned cg) {
  unsigned b = r * 64u + cg;
  return *(const bf16x8*)(smem + base + swz16(b));
}

// ---------------- fused weight transpose + bf16 convert: WT[n][k] = W[k][n] ----------------
struct TJob { const float* W; __bf16* WT; int K, N, Kp, tx, off; };
struct TJobs { TJob j[7]; };

__global__ __launch_bounds__(256) void transpose_all(TJobs js, int njobs)
{
  __shared__ float tile[64][65];
  int b = blockIdx.x;
  int ji = 0;
  #pragma unroll
  for (int i = 1; i < 7; ++i) if (i < njobs && b >= js.j[i].off) ji = i;
  const TJob jb = js.j[ji];
  int lb = b - jb.off;
  int bx = lb % jb.tx, by = lb / jb.tx;
  const int kb = bx * 64, nb = by * 64;
  const int tx = threadIdx.x & 63, ty = threadIdx.x >> 6;
  #pragma unroll
  for (int i = 0; i < 64; i += 4) {
    int k = kb + ty + i, n = nb + tx;
    tile[ty + i][tx] = (k < jb.K && n < jb.N) ? jb.W[(size_t)k * jb.N + n] : 0.f;
  }
  __syncthreads();
  #pragma unroll
  for (int i = 0; i < 64; i += 4) {
    int n = nb + ty + i, k = kb + tx;
    if (n < jb.N && k < jb.Kp) jb.WT[(size_t)n * jb.Kp + k] = f2bf(tile[tx][ty + i]);
  }
}

// ---------------- fused bottom MLP + embedding gather + interaction ----------------
// 512 blocks x 256 threads; 32 samples/block; wave w handles samples w*8..w*8+7 for interact.
// LDS layout (77824 B): h2s@0 [32][136], As@8704 [32][40], Bs@11264 [256][32],
//   h1s@27648 [32][264], h0s@44544 [32][520]. After layer2 barrier: st_w = 8704+w*8704
//   ([32][136] per wave) overlays As/Bs/h1s (all dead).
__global__ __launch_bounds__(256) void bottom_interact(
    const float* __restrict__ x, const int* __restrict__ xcat,
    const float* __restrict__ emb,
    const __bf16* __restrict__ w0t, const float* __restrict__ b0,
    const __bf16* __restrict__ w1t, const float* __restrict__ b1,
    const __bf16* __restrict__ w2t, const float* __restrict__ b2,
    __bf16* __restrict__ top_in)
{
  __shared__ __align__(16) char smem[77824];
  const int tid = threadIdx.x, lane = tid & 63, w = tid >> 6;
  const int r0 = blockIdx.x * 32;
  const int srow_b = lane >> 2;
  const int scol_b = (lane & 3) * 8;
  const unsigned rA = lane & 15, cgw = (lane >> 4) * 8;

  #define AS_B(r,c) (smem + 8704  + (r)*80   + (c)*2)
  #define BS_B(r,c) (smem + 11264 + (r)*64   + (c)*2)
  #define H1_B(r,c) (smem + 27648 + (r)*528  + (c)*2)
  #define H0_B(r,c) (smem + 44544 + (r)*1040 + (c)*2)
  #define H2_B(r,c) (smem +         (r)*272  + (c)*2)

  // ---- T14 issue-early: sample-0 embedding gather flies under the bottom phase ----
  auto ld_gather = [&](float4 (&buf)[13], int s) {
    const int* xs = xcat + (size_t)(r0 + w * 8 + s) * 26;
    #pragma unroll
    for (int i = 0; i < 13; ++i) {
      int fi = 2 * i + (lane >> 5);          // feature 0..25 (half-wave split)
      int ridx = xs[fi] & VOCAB_MASK;
      buf[i] = *(const float4*)(emb + (size_t)ridx * 128 + (lane & 31) * 4);
    }
  };
  float4 bufA[13], bufB[13];
  ld_gather(bufA, 0);

  // stage A: x rows -> bf16, zero-pad cols 13..39
  for (int idx = tid; idx < 32 * 40; idx += 256) {
    int row = idx / 40, k = idx - row * 40;
    float v = (k < 13) ? x[(size_t)(r0 + row) * 13 + k] : 0.f;
    *(__bf16*)AS_B(row, k) = f2bf(v);
  }

  // ---- layer 0: h0 = relu(A @ W0 + b0), N=512 in two 256-col passes, K=32 ----
  #pragma unroll
  for (int p = 0; p < 2; ++p) {
    __syncthreads();
    #pragma unroll
    for (int c = 0; c < 4; ++c) {
      int row = w * 64 + c * 16 + srow_b;
      GLDS16(w0t + (size_t)(p * 256 + row) * 32 + scol_b, BS_B(row, scol_b));
    }
    __syncthreads();
    bf16x8 a[2], bv[4];
    #pragma unroll
    for (int m = 0; m < 2; ++m) a[m] = *(const bf16x8*)AS_B(rA + m * 16, cgw);
    #pragma unroll
    for (int n = 0; n < 4; ++n) bv[n] = *(const bf16x8*)BS_B(w * 64 + n * 16 + rA, cgw);
    f32x4 acc[2][4] = {};
    #pragma unroll
    for (int m = 0; m < 2; ++m)
      #pragma unroll
      for (int n = 0; n < 4; ++n)
        acc[m][n] = __builtin_amdgcn_mfma_f32_16x16x32_bf16(a[m], bv[n], acc[m][n], 0, 0, 0);
    #pragma unroll
    for (int m = 0; m < 2; ++m)
      #pragma unroll
      for (int n = 0; n < 4; ++n) {
        int col = p * 256 + w * 64 + n * 16 + (int)rA;
        float bb = b0[col];
        #pragma unroll
        for (int r = 0; r < 4; ++r) {
          int row = m * 16 + (lane >> 4) * 4 + r;
          *(__bf16*)H0_B(row, col) = f2bf(fmaxf(acc[m][n][r] + bb, 0.f));
        }
      }
  }

  // ---- layer 1: h1 = relu(h0 @ W1 + b1), N=256, K=512 ----
  f32x4 acc1[2][4] = {};
  for (int k0 = 0; k0 < 512; k0 += 32) {
    __syncthreads();
    #pragma unroll
    for (int c = 0; c < 4; ++c) {
      int row = w * 64 + c * 16 + srow_b;
      GLDS16(w1t + (size_t)row * 512 + k0 + scol_b, BS_B(row, scol_b));
    }
    __syncthreads();
    bf16x8 a[2], bv[4];
    #pragma unroll
    for (int m = 0; m < 2; ++m) a[m] = *(const bf16x8*)H0_B(rA + m * 16, k0 + cgw);
    #pragma unroll
    for (int n = 0; n < 4; ++n) bv[n] = *(const bf16x8*)BS_B(w * 64 + n * 16 + rA, cgw);
    #pragma unroll
    for (int m = 0; m < 2; ++m)
      #pragma unroll
      for (int n = 0; n < 4; ++n)
        acc1[m][n] = __builtin_amdgcn_mfma_f32_16x16x32_bf16(a[m], bv[n], acc1[m][n], 0, 0, 0);
  }
  #pragma unroll
  for (int m = 0; m < 2; ++m)
    #pragma unroll
    for (int n = 0; n < 4; ++n) {
      int col = w * 64 + n * 16 + (int)rA;
      float bb = b1[col];
      #pragma unroll
      for (int r = 0; r < 4; ++r) {
        int row = m * 16 + (lane >> 4) * 4 + r;
        *(__bf16*)H1_B(row, col) = f2bf(fmaxf(acc1[m][n][r] + bb, 0.f));
      }
    }

  // ---- layer 2: h2 = relu(h1 @ W2 + b2), N=128, K=256 -> h2s (LDS only) ----
  f32x4 acc2[2][2] = {};
  for (int k0 = 0; k0 < 256; k0 += 32) {
    __syncthreads();
    #pragma unroll
    for (int c = 0; c < 2; ++c) {
      int row = w * 32 + c * 16 + srow_b;
      GLDS16(w2t + (size_t)row * 256 + k0 + scol_b, BS_B(row, scol_b));
    }
    __syncthreads();
    bf16x8 a[2], bv[2];
    #pragma unroll
    for (int m = 0; m < 2; ++m) a[m] = *(const bf16x8*)H1_B(rA + m * 16, k0 + cgw);
    #pragma unroll
    for (int n = 0; n < 2; ++n) bv[n] = *(const bf16x8*)BS_B(w * 32 + n * 16 + rA, cgw);
    #pragma unroll
    for (int m = 0; m < 2; ++m)
      #pragma unroll
      for (int n = 0; n < 2; ++n)
        acc2[m][n] = __builtin_amdgcn_mfma_f32_16x16x32_bf16(a[m], bv[n], acc2[m][n], 0, 0, 0);
  }
  #pragma unroll
  for (int m = 0; m < 2; ++m)
    #pragma unroll
    for (int n = 0; n < 2; ++n) {
      int col = w * 32 + n * 16 + (int)rA;
      float bb = b2[col];
      #pragma unroll
      for (int r = 0; r < 4; ++r) {
        int row = m * 16 + (lane >> 4) * 4 + r;
        *(__bf16*)H2_B(row, col) = f2bf(fmaxf(acc2[m][n][r] + bb, 0.f));
      }
    }

  __syncthreads();   // h2s complete; As/Bs/h0s/h1s dead -> st overlays them

  // ---- interact: per wave, 8 samples; st_w [32][136] @ 8704 + w*8704 ----
  char* st_w = smem + 8704 + (unsigned)w * 8704u;
  #pragma unroll
  for (int r = 27; r < 32; ++r) *(unsigned*)(st_w + r * 272 + lane * 4) = 0;

  #pragma unroll
  for (int s = 0; s < 8; ++s) {
    float4 (&cur)[13] = (s & 1) ? bufB : bufA;
    float4 (&nxt)[13] = (s & 1) ? bufA : bufB;
    const int sg = r0 + w * 8 + s;
    __bf16* op = top_in + (size_t)sg * 512;

    // row 0 = bot_out (from h2s) ; also copy to top_in cols 0..127; zero cols 506..511
    unsigned hv = *(const unsigned*)(smem + (unsigned)(w * 8 + s) * 272u + lane * 4);
    *(unsigned*)(st_w + lane * 4) = hv;
    ((unsigned*)op)[lane] = hv;
    if (lane < 3) ((unsigned*)op)[253 + lane] = 0;

    // rows 1..26: convert gathered fp32 -> bf16 (2 rows per original instr; 4 els/lane)
    #pragma unroll
    for (int i = 0; i < 13; ++i) {
      int row = 1 + 2 * i + (lane >> 5);
      float4 v = cur[i];
      bf16x4 bv;
      bv[0] = f2bf(v.x); bv[1] = f2bf(v.y); bv[2] = f2bf(v.z); bv[3] = f2bf(v.w);
      *(bf16x4*)(st_w + row * 272 + (lane & 31) * 8) = bv;
    }
    if (s < 7) ld_gather(nxt, s + 1);   // next sample's loads fly under the MFMAs

    asm volatile("s_waitcnt lgkmcnt(0)" ::: "memory");
    __builtin_amdgcn_sched_barrier(0);

    f32x4 a00 = {}, a01 = {}, a11 = {};
    #pragma unroll
    for (int k0 = 0; k0 < 4; ++k0) {
      bf16x8 fr0 = *(const bf16x8*)(st_w + (lane & 15) * 272 + k0 * 64 + (lane >> 4) * 16);
      bf16x8 fr1 = *(const bf16x8*)(st_w + (16 + (lane & 15)) * 272 + k0 * 64 + (lane >> 4) * 16);
      a00 = __builtin_amdgcn_mfma_f32_16x16x32_bf16(fr0, fr0, a00, 0, 0, 0);
      a01 = __builtin_amdgcn_mfma_f32_16x16x32_bf16(fr0, fr1, a01, 0, 0, 0);
      a11 = __builtin_amdgcn_mfma_f32_16x16x32_bf16(fr1, fr1, a11, 0, 0, 0);
    }

    const int jc = lane & 15, rb = (lane >> 4) * 4;
    #pragma unroll
    for (int r = 0; r < 4; ++r) {
      {
        int i = rb + r, j = jc;
        if (i <= j) op[128 + i * 27 - i * (i - 1) / 2 + (j - i)] = f2bf(a00[r]);
      }
      {
        int i = rb + r, j = 16 + jc;
        if (j <= 26) op[128 + i * 27 - i * (i - 1) / 2 + (j - i)] = f2bf(a01[r]);
      }
      {
        int i = 16 + rb + r, j = 16 + jc;
        if (i <= j && j <= 26) op[128 + i * 27 - i * (i - 1) / 2 + (j - i)] = f2bf(a11[r]);
      }
    }
  }
  #undef AS_B
  #undef BS_B
  #undef H1_B
  #undef H0_B
  #undef H2_B
}

// ---------------- 256x256 phase-interleaved GEMM (T1+T2+T3+T4+T5), BK=32 ----------------
__global__ __launch_bounds__(512, 2) void gemm_8ph(
    const __bf16* __restrict__ A, const __bf16* __restrict__ WT,
    const float* __restrict__ bias, __bf16* __restrict__ C,
    int N, int sA, int K, int gm)
{
  __shared__ __align__(16) char smem[65536];
  const int tid = threadIdx.x, lane = tid & 63, w = tid >> 6;
  const int wm = w >> 2, wn = w & 3;

  int nb = gridDim.x;
  int id = blockIdx.x;
  int swz = ((nb & 7) == 0) ? ((id & 7) * (nb >> 3) + (id >> 3)) : id;
  const int m0 = (swz % gm) * 256, n0 = (swz / gm) * 256;

  unsigned Ld[2]; const __bf16* sAp[2]; const __bf16* sBp[2];
  #pragma unroll
  for (int h = 0; h < 2; ++h) {
    unsigned L = h * 8192u + (unsigned)w * 1024u + (unsigned)lane * 16u;
    unsigned Ls = swz16(L);
    Ld[h] = L;
    int srow = Ls >> 6, scb = Ls & 63;
    sAp[h] = A  + (size_t)(m0 + srow) * sA + (scb >> 1);
    sBp[h] = WT + (size_t)(n0 + srow) * K  + (scb >> 1);
  }

  #define STAGE_A(kt, p) { GLDS16(sAp[0] + (kt)*32, smem + (p)*32768 + Ld[0]); \
                           GLDS16(sAp[1] + (kt)*32, smem + (p)*32768 + Ld[1]); }
  #define STAGE_B(kt, p) { GLDS16(sBp[0] + (kt)*32, smem + (p)*32768 + 16384 + Ld[0]); \
                           GLDS16(sBp[1] + (kt)*32, smem + (p)*32768 + 16384 + Ld[1]); }

  const unsigned cg = (lane >> 4) * 16u;
  const unsigned rA = (lane & 15);

  f32x4 acc[8][4] = {};
  const int iters = (K >> 5) >> 1;

  STAGE_B(0, 0); STAGE_A(0, 0); STAGE_B(1, 1);
  asm volatile("s_waitcnt vmcnt(2)" ::: "memory");
  __builtin_amdgcn_s_barrier();
  __builtin_amdgcn_sched_barrier(0);

  for (int i = 0; i < iters; ++i) {
    const int t = 2 * i;
    const bool more = (i + 1 < iters);

    bf16x8 a0[4], b0[4];
    #pragma unroll
    for (int m = 0; m < 4; ++m) a0[m] = lds_frag(smem, 0, wm * 128 + m * 16 + rA, cg);
    #pragma unroll
    for (int n = 0; n < 4; ++n) b0[n] = lds_frag(smem, 16384, wn * 64 + n * 16 + rA, cg);
    STAGE_A(t + 1, 1);
    __builtin_amdgcn_s_barrier();
    asm volatile("s_waitcnt lgkmcnt(0)" ::: "memory");
    __builtin_amdgcn_sched_barrier(0);
    __builtin_amdgcn_s_setprio(1);
    #pragma unroll
    for (int m = 0; m < 4; ++m)
      #pragma unroll
      for (int n = 0; n < 4; ++n)
        acc[m][n] = __builtin_amdgcn_mfma_f32_16x16x32_bf16(a0[m], b0[n], acc[m][n], 0, 0, 0);
    __builtin_amdgcn_s_setprio(0);
    __builtin_amdgcn_s_barrier();
    __builtin_amdgcn_sched_barrier(0);

    bf16x8 a1[4];
    #pragma unroll
    for (int m = 0; m < 4; ++m) a1[m] = lds_frag(smem, 0, wm * 128 + 64 + m * 16 + rA, cg);
    if (more) STAGE_B(t + 2, 0);
    __builtin_amdgcn_s_barrier();
    asm volatile("s_waitcnt lgkmcnt(0)" ::: "memory");
    __builtin_amdgcn_sched_barrier(0);
    __builtin_amdgcn_s_setprio(1);
    #pragma unroll
    for (int m = 0; m < 4; ++m)
      #pragma unroll
      for (int n = 0; n < 4; ++n)
        acc[4 + m][n] = __builtin_amdgcn_mfma_f32_16x16x32_bf16(a1[m], b0[n], acc[4 + m][n], 0, 0, 0);
    __builtin_amdgcn_s_setprio(0);
    if (more) { asm volatile("s_waitcnt vmcnt(2)" ::: "memory"); }
    else      { asm volatile("s_waitcnt vmcnt(0)" ::: "memory"); }
    __builtin_amdgcn_s_barrier();
    __builtin_amdgcn_sched_barrier(0);

    bf16x8 a2[4], b2[4];
    #pragma unroll
    for (int m = 0; m < 4; ++m) a2[m] = lds_frag(smem, 32768, wm * 128 + m * 16 + rA, cg);
    #pragma unroll
    for (int n = 0; n < 4; ++n) b2[n] = lds_frag(smem, 32768 + 16384, wn * 64 + n * 16 + rA, cg);
    if (more) STAGE_A(t + 2, 0);
    __builtin_amdgcn_s_barrier();
    asm volatile("s_waitcnt lgkmcnt(0)" ::: "memory");
    __builtin_amdgcn_sched_barrier(0);
    __builtin_amdgcn_s_setprio(1);
    #pragma unroll
    for (int m = 0; m < 4; ++m)
      #pragma unroll
      for (int n = 0; n < 4; ++n)
        acc[m][n] = __builtin_amdgcn_mfma_f32_16x16x32_bf16(a2[m], b2[n], acc[m][n], 0, 0, 0);
    __builtin_amdgcn_s_setprio(0);
    __builtin_amdgcn_s_barrier();
    __builtin_amdgcn_sched_barrier(0);

    bf16x8 a3[4];
    #pragma unroll
    for (int m = 0; m < 4; ++m) a3[m] = lds_frag(smem, 32768, wm * 128 + 64 + m * 16 + rA, cg);
    if (more) STAGE_B(t + 3, 1);
    __builtin_amdgcn_s_barrier();
    asm volatile("s_waitcnt lgkmcnt(0)" ::: "memory");
    __builtin_amdgcn_sched_barrier(0);
    __builtin_amdgcn_s_setprio(1);
    #pragma unroll
    for (int m = 0; m < 4; ++m)
      #pragma unroll
      for (int n = 0; n < 4; ++n)
        acc[4 + m][n] = __builtin_amdgcn_mfma_f32_16x16x32_bf16(a3[m], b2[n], acc[4 + m][n], 0, 0, 0);
    __builtin_amdgcn_s_setprio(0);
    if (more) { asm volatile("s_waitcnt vmcnt(2)" ::: "memory"); }
    __builtin_amdgcn_s_barrier();
    __builtin_amdgcn_sched_barrier(0);
  }

  #pragma unroll
  for (int n = 0; n < 4; ++n) {
    int col = n0 + wn * 64 + n * 16 + (lane & 15);
    float bv = bias[col];
    #pragma unroll
    for (int m = 0; m < 8; ++m) {
      #pragma unroll
      for (int r = 0; r < 4; ++r) {
        int row = m0 + wm * 128 + m * 16 + (lane >> 4) * 4 + r;
        float v = fmaxf(acc[m][n][r] + bv, 0.f);
        C[(size_t)row * N + col] = f2bf(v);
      }
    }
  }
  #undef STAGE_A
  #undef STAGE_B
}

// ---------------- 256x128-tile phase-interleaved GEMM ----------------
__global__ __launch_bounds__(512, 2) void gemm_8ph_n128(
    const __bf16* __restrict__ A, const __bf16* __restrict__ WT,
    const float* __restrict__ bias, __bf16* __restrict__ C,
    int N, int sA, int K, int gm)
{
  __shared__ __align__(16) char smem[49152];
  const int tid = threadIdx.x, lane = tid & 63, w = tid >> 6;
  const int wm = w >> 1, wn = w & 1;

  int nb = gridDim.x;
  int id = blockIdx.x;
  int swz = ((nb & 7) == 0) ? ((id & 7) * (nb >> 3) + (id >> 3)) : id;
  const int m0 = (swz % gm) * 256, n0 = (swz / gm) * 128;

  unsigned Ld[2]; const __bf16* sAp[2]; const __bf16* sBp0;
  #pragma unroll
  for (int h = 0; h < 2; ++h) {
    unsigned L = h * 8192u + (unsigned)w * 1024u + (unsigned)lane * 16u;
    unsigned Ls = swz16(L);
    Ld[h] = L;
    int srow = Ls >> 6, scb = Ls & 63;
    sAp[h] = A + (size_t)(m0 + srow) * sA + (scb >> 1);
  }
  {
    unsigned L = (unsigned)w * 1024u + (unsigned)lane * 16u;
    unsigned Ls = swz16(L);
    int srow = Ls >> 6, scb = Ls & 63;
    sBp0 = WT + (size_t)(n0 + srow) * K + (scb >> 1);
  }

  #define STAGE_A2(kt, p) { GLDS16(sAp[0] + (kt)*32, smem + (p)*24576 + Ld[0]); \
                            GLDS16(sAp[1] + (kt)*32, smem + (p)*24576 + Ld[1]); }
  #define STAGE_B1(kt, p) { GLDS16(sBp0 + (kt)*32, smem + (p)*24576 + 16384 + Ld[0]); }

  const unsigned cg = (lane >> 4) * 16u;
  const unsigned rA = (lane & 15);

  f32x4 acc[4][4] = {};
  const int iters = (K >> 5) >> 1;

  STAGE_B1(0, 0); STAGE_A2(0, 0); STAGE_B1(1, 1);
  asm volatile("s_waitcnt vmcnt(1)" ::: "memory");
  __builtin_amdgcn_s_barrier();
  __builtin_amdgcn_sched_barrier(0);

  for (int i = 0; i < iters; ++i) {
    const int t = 2 * i;
    const bool more = (i + 1 < iters);

    bf16x8 a0[2], b0[4];
    #pragma unroll
    for (int m = 0; m < 2; ++m) a0[m] = lds_frag(smem, 0, wm * 64 + m * 16 + rA, cg);
    #pragma unroll
    for (int n = 0; n < 4; ++n) b0[n] = lds_frag(smem, 16384, wn * 64 + n * 16 + rA, cg);
    STAGE_A2(t + 1, 1);
    __builtin_amdgcn_s_barrier();
    asm volatile("s_waitcnt lgkmcnt(0)" ::: "memory");
    __builtin_amdgcn_sched_barrier(0);
    __builtin_amdgcn_s_setprio(1);
    #pragma unroll
    for (int m = 0; m < 2; ++m)
      #pragma unroll
      for (int n = 0; n < 4; ++n)
        acc[m][n] = __builtin_amdgcn_mfma_f32_16x16x32_bf16(a0[m], b0[n], acc[m][n], 0, 0, 0);
    __builtin_amdgcn_s_setprio(0);
    __builtin_amdgcn_s_barrier();
    __builtin_amdgcn_sched_barrier(0);

    bf16x8 a1[2];
    #pragma unroll
    for (int m = 0; m < 2; ++m) a1[m] = lds_frag(smem, 0, wm * 64 + 32 + m * 16 + rA, cg);
    if (more) STAGE_B1(t + 2, 0);
    __builtin_amdgcn_s_barrier();
    asm volatile("s_waitcnt lgkmcnt(0)" ::: "memory");
    __builtin_amdgcn_sched_barrier(0);
    __builtin_amdgcn_s_setprio(1);
    #pragma unroll
    for (int m = 0; m < 2; ++m)
      #pragma unroll
      for (int n = 0; n < 4; ++n)
        acc[2 + m][n] = __builtin_amdgcn_mfma_f32_16x16x32_bf16(a1[m], b0[n], acc[2 + m][n], 0, 0, 0);
    __builtin_amdgcn_s_setprio(0);
    if (more) { asm volatile("s_waitcnt vmcnt(1)" ::: "memory"); }
    else      { asm volatile("s_waitcnt vmcnt(0)" ::: "memory"); }
    __builtin_amdgcn_s_barrier();
    __builtin_amdgcn_sched_barrier(0);

    bf16x8 a2[2], b2[4];
    #pragma unroll
    for (int m = 0; m < 2; ++m) a2[m] = lds_frag(smem, 24576, wm * 64 + m * 16 + rA, cg);
    #pragma unroll
    for (int n = 0; n < 4; ++n) b2[n] = lds_frag(smem, 24576 + 16384, wn * 64 + n * 16 + rA, cg);
    if (more) STAGE_A2(t + 2, 0);
    __builtin_amdgcn_s_barrier();
    asm volatile("s_waitcnt lgkmcnt(0)" ::: "memory");
    __builtin_amdgcn_sched_barrier(0);
    __builtin_amdgcn_s_setprio(1);
    #pragma unroll
    for (int m = 0; m < 2; ++m)
      #pragma unroll
      for (int n = 0; n < 4; ++n)
        acc[m][n] = __builtin_amdgcn_mfma_f32_16x16x32_bf16(a2[m], b2[n], acc[m][n], 0, 0, 0);
    __builtin_amdgcn_s_setprio(0);
    __builtin_amdgcn_s_barrier();
    __builtin_amdgcn_sched_barrier(0);

    bf16x8 a3[2];
    #pragma unroll
    for (int m = 0; m < 2; ++m) a3[m] = lds_frag(smem, 24576, wm * 64 + 32 + m * 16 + rA, cg);
    if (more) STAGE_B1(t + 3, 1);
    __builtin_amdgcn_s_barrier();
    asm volatile("s_waitcnt lgkmcnt(0)" ::: "memory");
    __builtin_amdgcn_sched_barrier(0);
    __builtin_amdgcn_s_setprio(1);
    #pragma unroll
    for (int m = 0; m < 2; ++m)
      #pragma unroll
      for (int n = 0; n < 4; ++n)
        acc[2 + m][n] = __builtin_amdgcn_mfma_f32_16x16x32_bf16(a3[m], b2[n], acc[2 + m][n], 0, 0, 0);
    __builtin_amdgcn_s_setprio(0);
    if (more) { asm volatile("s_waitcnt vmcnt(1)" ::: "memory"); }
    __builtin_amdgcn_s_barrier();
    __builtin_amdgcn_sched_barrier(0);
  }

  #pragma unroll
  for (int n = 0; n < 4; ++n) {
    int col = n0 + wn * 64 + n * 16 + (lane & 15);
    float bv = bias[col];
    #pragma unroll
    for (int m = 0; m < 4; ++m) {
      #pragma unroll
      for (int r = 0; r < 4; ++r) {
        int row = m0 + wm * 64 + m * 16 + (lane >> 4) * 4 + r;
        float v = fmaxf(acc[m][n][r] + bv, 0.f);
        C[(size_t)row * N + col] = f2bf(v);
      }
    }
  }
  #undef STAGE_A2
  #undef STAGE_B1
}

// ---------------- fused t3 GEMM (128x256 tile, N=256 K=512) + final dot ----------------
// out[row] = dot(relu(t2[row] @ W3 + b3), w4) + b4
__global__ __launch_bounds__(256) void gemm_t3_final(
    const __bf16* __restrict__ A, const __bf16* __restrict__ WT,
    const float* __restrict__ b3, const float* __restrict__ w4,
    const float* __restrict__ b4, float* __restrict__ out)
{
  __shared__ __bf16 As[128][32];
  __shared__ __bf16 Bs[256][32];
  __shared__ float red[128][4];
  const int tid = threadIdx.x, lane = tid & 63, wid = tid >> 6;
  const int m0 = blockIdx.x * 128;
  const int srow = wid * 16 + (lane >> 2);
  const int scol = (lane & 3) * 8;
  const __bf16* Ag0 = A + (size_t)(m0 + srow) * 512 + scol;
  const __bf16* Ag1 = A + (size_t)(m0 + srow + 64) * 512 + scol;

  f32x4 acc[8][4] = {};

  for (int k0 = 0; k0 < 512; k0 += 32) {
    __syncthreads();
    GLDS16(Ag0 + k0, &As[srow][scol]);
    GLDS16(Ag1 + k0, &As[srow + 64][scol]);
    #pragma unroll
    for (int c = 0; c < 4; ++c) {
      int br = wid * 64 + c * 16 + (lane >> 2);
      GLDS16(WT + (size_t)br * 512 + k0 + scol, &Bs[br][scol]);
    }
    __syncthreads();

    bf16x8 af[8], bfv[4];
    #pragma unroll
    for (int m = 0; m < 8; ++m)
      af[m] = *(const bf16x8*)&As[m * 16 + (lane & 15)][(lane >> 4) * 8];
    #pragma unroll
    for (int n = 0; n < 4; ++n)
      bfv[n] = *(const bf16x8*)&Bs[wid * 64 + n * 16 + (lane & 15)][(lane >> 4) * 8];
    #pragma unroll
    for (int m = 0; m < 8; ++m)
      #pragma unroll
      for (int n = 0; n < 4; ++n)
        acc[m][n] = __builtin_amdgcn_mfma_f32_16x16x32_bf16(af[m], bfv[n], acc[m][n], 0, 0, 0);
  }

  // epilogue: relu + b3, dot with w4, reduce
  float pd[8][4];
  #pragma unroll
  for (int m = 0; m < 8; ++m)
    #pragma unroll
    for (int r = 0; r < 4; ++r) pd[m][r] = 0.f;
  #pragma unroll
  for (int n = 0; n < 4; ++n) {
    int col = wid * 64 + n * 16 + (lane & 15);
    float bb = b3[col];
    float wc = w4[col];
    #pragma unroll
    for (int m = 0; m < 8; ++m)
      #pragma unroll
      for (int r = 0; r < 4; ++r)
        pd[m][r] += fmaxf(acc[m][n][r] + bb, 0.f) * wc;
  }
  #pragma unroll
  for (int m = 0; m < 8; ++m)
    #pragma unroll
    for (int r = 0; r < 4; ++r) {
      float s = pd[m][r];
      s += __shfl_xor(s, 1); s += __shfl_xor(s, 2);
      s += __shfl_xor(s, 4); s += __shfl_xor(s, 8);
      if ((lane & 15) == 0) red[m * 16 + (lane >> 4) * 4 + r][wid] = s;
    }
  __syncthreads();
  if (tid < 128)
    out[m0 + tid] = red[tid][0] + red[tid][1] + red[tid][2] + red[tid][3] + b4[0];
}

extern "C" void kernel_launch(void* const* d_in, const int* in_sizes, int n_in,
                              void* d_out, int out_size, void* d_ws, size_t ws_size,
                              hipStream_t stream)
{
  const float* x_dense = (const float*)d_in[0];
  const int*   x_cat   = (const int*)d_in[1];
  const float* emb     = (const float*)d_in[2];
  const float* wb[3] = {(const float*)d_in[3], (const float*)d_in[5], (const float*)d_in[7]};
  const float* bb[3] = {(const float*)d_in[4], (const float*)d_in[6], (const float*)d_in[8]};
  const float* wt[5] = {(const float*)d_in[9],  (const float*)d_in[11], (const float*)d_in[13],
                        (const float*)d_in[15], (const float*)d_in[17]};
  const float* bt[5] = {(const float*)d_in[10], (const float*)d_in[12], (const float*)d_in[14],
                        (const float*)d_in[16], (const float*)d_in[18]};
  float* out = (float*)d_out;

  char* ws = (char*)d_ws;
  const size_t MB = 1ull << 20;
  __bf16* wt_b0 = (__bf16*)(ws + 0 * MB);   // 512x32
  __bf16* wt_b1 = (__bf16*)(ws + 1 * MB);   // 256x512
  __bf16* wt_b2 = (__bf16*)(ws + 2 * MB);   // 128x256
  __bf16* wt_t0 = (__bf16*)(ws + 3 * MB);   // 1024x512
  __bf16* wt_t1 = (__bf16*)(ws + 4 * MB);   // 1024x1024
  __bf16* wt_t2 = (__bf16*)(ws + 6 * MB);   // 512x1024
  __bf16* wt_t3 = (__bf16*)(ws + 7 * MB);   // 256x512
  __bf16* top_in = (__bf16*)(ws + 12 * MB);  // 16MB (region C)
  __bf16* t2     = (__bf16*)(ws + 12 * MB);  // (region C, after top_in dead)
  __bf16* t1     = (__bf16*)(ws + 28 * MB);  // 32MB (region A)
  __bf16* t0     = (__bf16*)(ws + 60 * MB);  // 32MB (region B)

  // ---- fused weight prep (1 dispatch) ----
  TJobs js;
  const float* Ws[7] = {wb[0], wb[1], wb[2], wt[0], wt[1], wt[2], wt[3]};
  __bf16* WTs[7] = {wt_b0, wt_b1, wt_b2, wt_t0, wt_t1, wt_t2, wt_t3};
  int Ks[7]  = {13, 512, 256, 506, 1024, 1024, 512};
  int Ns[7]  = {512, 256, 128, 1024, 1024, 512, 256};
  int Kps[7] = {32, 512, 256, 512, 1024, 1024, 512};
  int off = 0;
  for (int i = 0; i < 7; ++i) {
    int tx = (Kps[i] + 63) / 64, ty = (Ns[i] + 63) / 64;
    js.j[i] = TJob{Ws[i], WTs[i], Ks[i], Ns[i], Kps[i], tx, off};
    off += tx * ty;
  }
  transpose_all<<<dim3(off), dim3(256), 0, stream>>>(js, 7);

  // ---- fused bottom MLP + embedding gather + interaction ----
  bottom_interact<<<dim3(BATCH / 32), dim3(256), 0, stream>>>(
      x_dense, x_cat, emb, wt_b0, bb[0], wt_b1, bb[1], wt_b2, bb[2], top_in);

  // ---- top MLP ----
  gemm_8ph<<<dim3(256), dim3(512), 0, stream>>>(top_in, wt_t0, bt[0], t0, 1024, 512, 512, 64);
  gemm_8ph<<<dim3(256), dim3(512), 0, stream>>>(t0, wt_t1, bt[1], t1, 1024, 1024, 1024, 64);
  gemm_8ph_n128<<<dim3(256), dim3(512), 0, stream>>>(t1, wt_t2, bt[2], t2, 512, 1024, 1024, 64);

  // ---- fused t3 + final ----
  gemm_t3_final<<<dim3(128), dim3(256), 0, stream>>>(t2, wt_t3, bt[3], wt[4], bt[4], out);
}

// Round 7
// 189.225 us; speedup vs baseline: 1.7189x; 1.0432x over previous
//
#include <hip/hip_runtime.h>
#include <cstdint>
#include <cstddef>

#define BATCH 16384
#define VOCAB_MASK (4194304 - 1)

typedef __attribute__((ext_vector_type(4))) float f32x4;
typedef __attribute__((ext_vector_type(8))) __bf16 bf16x8;
typedef __attribute__((ext_vector_type(4))) __bf16 bf16x4;

static_assert(sizeof(bf16x8) == 16, "bf16x8 must be 16 bytes");

static __device__ __forceinline__ __bf16 f2bf(float f) {
  union { float f; unsigned u; } in; in.f = f;
  unsigned r = in.u + 0x7FFF + ((in.u >> 16) & 1);
  union { unsigned short s; __bf16 b; } out; out.s = (unsigned short)(r >> 16);
  return out.b;
}
static __device__ __forceinline__ float bf2f(__bf16 b) {
  union { __bf16 b; unsigned short s; } in; in.b = b;
  union { unsigned u; float f; } out; out.u = ((unsigned)in.s) << 16;
  return out.f;
}

// async global->LDS, 16B per lane. LDS dest must be wave-uniform base + lane*16.
#define GLDS16(g, l) __builtin_amdgcn_global_load_lds( \
    (const __attribute__((address_space(1))) unsigned int*)(g), \
    (__attribute__((address_space(3))) unsigned int*)(l), 16, 0, 0)

// swizzle: XOR 16B-chunk index bits (involution)
static __device__ __forceinline__ unsigned swz16(unsigned b) {
  return b ^ ((((b >> 6) & 3u) ^ ((b >> 8) & 3u)) << 4);
}
static __device__ __forceinline__ bf16x8 lds_frag(const char* smem, unsigned base,
                                                  unsigned r, unsigned cg) {
  unsigned b = r * 64u + cg;
  return *(const bf16x8*)(smem + base + swz16(b));
}

// ---------------- fused weight transpose + bf16 convert: WT[n][k] = W[k][n] ----------------
struct TJob { const float* W; __bf16* WT; int K, N, Kp, tx, off; };
struct TJobs { TJob j[7]; };

__global__ __launch_bounds__(256) void transpose_all(TJobs js, int njobs)
{
  __shared__ float tile[64][65];
  int b = blockIdx.x;
  int ji = 0;
  #pragma unroll
  for (int i = 1; i < 7; ++i) if (i < njobs && b >= js.j[i].off) ji = i;
  const TJob jb = js.j[ji];
  int lb = b - jb.off;
  int bx = lb % jb.tx, by = lb / jb.tx;
  const int kb = bx * 64, nb = by * 64;
  const int tx = threadIdx.x & 63, ty = threadIdx.x >> 6;
  #pragma unroll
  for (int i = 0; i < 64; i += 4) {
    int k = kb + ty + i, n = nb + tx;
    tile[ty + i][tx] = (k < jb.K && n < jb.N) ? jb.W[(size_t)k * jb.N + n] : 0.f;
  }
  __syncthreads();
  #pragma unroll
  for (int i = 0; i < 64; i += 4) {
    int n = nb + ty + i, k = kb + tx;
    if (n < jb.N && k < jb.Kp) jb.WT[(size_t)n * jb.Kp + k] = f2bf(tile[tx][ty + i]);
  }
}

// ---------------- fused bottom MLP: x(13) -> 512 -> 256 -> 128, all in LDS ----------------
__global__ __launch_bounds__(256) void bottom_fused(
    const float* __restrict__ x,
    const __bf16* __restrict__ w0t, const float* __restrict__ b0,
    const __bf16* __restrict__ w1t, const float* __restrict__ b1,
    const __bf16* __restrict__ w2t, const float* __restrict__ b2,
    __bf16* __restrict__ h2out)
{
  __shared__ __bf16 h0s[32][520];
  __shared__ __bf16 h1s[32][264];
  __shared__ __bf16 As[32][40];
  __shared__ __bf16 Bs[256][32];
  const int tid = threadIdx.x, lane = tid & 63, w = tid >> 6;
  const int r0 = blockIdx.x * 32;
  const int srow_b = lane >> 2;
  const int scol_b = (lane & 3) * 8;
  const unsigned rA = lane & 15, cgw = (lane >> 4) * 8;

  for (int idx = tid; idx < 32 * 40; idx += 256) {
    int row = idx / 40, k = idx - row * 40;
    float v = (k < 13) ? x[(size_t)(r0 + row) * 13 + k] : 0.f;
    As[row][k] = f2bf(v);
  }

  #pragma unroll
  for (int p = 0; p < 2; ++p) {
    __syncthreads();
    #pragma unroll
    for (int c = 0; c < 4; ++c) {
      int row = w * 64 + c * 16 + srow_b;
      GLDS16(w0t + (size_t)(p * 256 + row) * 32 + scol_b, &Bs[row][scol_b]);
    }
    __syncthreads();
    bf16x8 a[2], bv[4];
    #pragma unroll
    for (int m = 0; m < 2; ++m) a[m] = *(const bf16x8*)&As[rA + m * 16][cgw];
    #pragma unroll
    for (int n = 0; n < 4; ++n) bv[n] = *(const bf16x8*)&Bs[w * 64 + n * 16 + rA][cgw];
    f32x4 acc[2][4] = {};
    #pragma unroll
    for (int m = 0; m < 2; ++m)
      #pragma unroll
      for (int n = 0; n < 4; ++n)
        acc[m][n] = __builtin_amdgcn_mfma_f32_16x16x32_bf16(a[m], bv[n], acc[m][n], 0, 0, 0);
    #pragma unroll
    for (int m = 0; m < 2; ++m)
      #pragma unroll
      for (int n = 0; n < 4; ++n) {
        int col = p * 256 + w * 64 + n * 16 + (int)rA;
        float bb = b0[col];
        #pragma unroll
        for (int r = 0; r < 4; ++r) {
          int row = m * 16 + (lane >> 4) * 4 + r;
          h0s[row][col] = f2bf(fmaxf(acc[m][n][r] + bb, 0.f));
        }
      }
  }

  f32x4 acc1[2][4] = {};
  for (int k0 = 0; k0 < 512; k0 += 32) {
    __syncthreads();
    #pragma unroll
    for (int c = 0; c < 4; ++c) {
      int row = w * 64 + c * 16 + srow_b;
      GLDS16(w1t + (size_t)row * 512 + k0 + scol_b, &Bs[row][scol_b]);
    }
    __syncthreads();
    bf16x8 a[2], bv[4];
    #pragma unroll
    for (int m = 0; m < 2; ++m) a[m] = *(const bf16x8*)&h0s[rA + m * 16][k0 + cgw];
    #pragma unroll
    for (int n = 0; n < 4; ++n) bv[n] = *(const bf16x8*)&Bs[w * 64 + n * 16 + rA][cgw];
    #pragma unroll
    for (int m = 0; m < 2; ++m)
      #pragma unroll
      for (int n = 0; n < 4; ++n)
        acc1[m][n] = __builtin_amdgcn_mfma_f32_16x16x32_bf16(a[m], bv[n], acc1[m][n], 0, 0, 0);
  }
  #pragma unroll
  for (int m = 0; m < 2; ++m)
    #pragma unroll
    for (int n = 0; n < 4; ++n) {
      int col = w * 64 + n * 16 + (int)rA;
      float bb = b1[col];
      #pragma unroll
      for (int r = 0; r < 4; ++r) {
        int row = m * 16 + (lane >> 4) * 4 + r;
        h1s[row][col] = f2bf(fmaxf(acc1[m][n][r] + bb, 0.f));
      }
    }

  f32x4 acc2[2][2] = {};
  for (int k0 = 0; k0 < 256; k0 += 32) {
    __syncthreads();
    #pragma unroll
    for (int c = 0; c < 2; ++c) {
      int row = w * 32 + c * 16 + srow_b;
      GLDS16(w2t + (size_t)row * 256 + k0 + scol_b, &Bs[row][scol_b]);
    }
    __syncthreads();
    bf16x8 a[2], bv[2];
    #pragma unroll
    for (int m = 0; m < 2; ++m) a[m] = *(const bf16x8*)&h1s[rA + m * 16][k0 + cgw];
    #pragma unroll
    for (int n = 0; n < 2; ++n) bv[n] = *(const bf16x8*)&Bs[w * 32 + n * 16 + rA][cgw];
    #pragma unroll
    for (int m = 0; m < 2; ++m)
      #pragma unroll
      for (int n = 0; n < 2; ++n)
        acc2[m][n] = __builtin_amdgcn_mfma_f32_16x16x32_bf16(a[m], bv[n], acc2[m][n], 0, 0, 0);
  }
  #pragma unroll
  for (int m = 0; m < 2; ++m)
    #pragma unroll
    for (int n = 0; n < 2; ++n) {
      int col = w * 32 + n * 16 + (int)rA;
      float bb = b2[col];
      #pragma unroll
      for (int r = 0; r < 4; ++r) {
        int row = m * 16 + (lane >> 4) * 4 + r;
        h2out[(size_t)(r0 + row) * 128 + col] = f2bf(fmaxf(acc2[m][n][r] + bb, 0.f));
      }
    }
}

// ---------------- embedding gather (float4) + MFMA pairwise interaction ----------------
// 1 wave per sample, 4 samples/block, 4096 blocks (~4 blocks/CU).
__global__ __launch_bounds__(256) void interact_mfma(
    const __bf16* __restrict__ bot, const int* __restrict__ xcat,
    const float* __restrict__ emb, __bf16* __restrict__ top_in)
{
  __shared__ __bf16 st[4][32][136];
  const int tid = threadIdx.x, lane = tid & 63, w = tid >> 6;
  const int s = blockIdx.x * 4 + w;

  // gather 26 rows, 2 rows per instruction (16B/lane float4; half-wave per row)
  const int* xr = xcat + (size_t)s * 26;
  float4 buf[13];
  #pragma unroll
  for (int i = 0; i < 13; ++i) {
    int fi = 2 * i + (lane >> 5);
    int ridx = xr[fi] & VOCAB_MASK;
    buf[i] = *(const float4*)(emb + (size_t)ridx * 128 + (lane & 31) * 4);
  }

  // row 0 = bot_out (bf16)
  *(unsigned*)&st[w][0][lane * 2] = *(const unsigned*)(bot + (size_t)s * 128 + lane * 2);
  // rows 27..31 zero
  #pragma unroll
  for (int r = 27; r < 32; ++r) *(unsigned*)&st[w][r][lane * 2] = 0u;
  // rows 1..26: fp32 -> bf16, 4 els/lane
  #pragma unroll
  for (int i = 0; i < 13; ++i) {
    int row = 1 + 2 * i + (lane >> 5);
    bf16x4 bv;
    bv[0] = f2bf(buf[i].x); bv[1] = f2bf(buf[i].y);
    bv[2] = f2bf(buf[i].z); bv[3] = f2bf(buf[i].w);
    *(bf16x4*)&st[w][row][(lane & 31) * 4] = bv;
  }

  f32x4 a00 = {}, a01 = {}, a11 = {};
  #pragma unroll
  for (int k0 = 0; k0 < 4; ++k0) {
    bf16x8 fr0 = *(const bf16x8*)&st[w][(lane & 15)][k0 * 32 + (lane >> 4) * 8];
    bf16x8 fr1 = *(const bf16x8*)&st[w][16 + (lane & 15)][k0 * 32 + (lane >> 4) * 8];
    a00 = __builtin_amdgcn_mfma_f32_16x16x32_bf16(fr0, fr0, a00, 0, 0, 0);
    a01 = __builtin_amdgcn_mfma_f32_16x16x32_bf16(fr0, fr1, a01, 0, 0, 0);
    a11 = __builtin_amdgcn_mfma_f32_16x16x32_bf16(fr1, fr1, a11, 0, 0, 0);
  }

  __bf16* op = top_in + (size_t)s * 512;
  ((unsigned*)op)[lane] = *(const unsigned*)&st[w][0][lane * 2];
  if (lane < 3) ((unsigned*)op)[253 + lane] = 0u;   // cols 506..511 = 0

  const int jc = lane & 15, rb = (lane >> 4) * 4;
  #pragma unroll
  for (int r = 0; r < 4; ++r) {
    {
      int i = rb + r, j = jc;
      if (i <= j) op[128 + i * 27 - i * (i - 1) / 2 + (j - i)] = f2bf(a00[r]);
    }
    {
      int i = rb + r, j = 16 + jc;
      if (j <= 26) op[128 + i * 27 - i * (i - 1) / 2 + (j - i)] = f2bf(a01[r]);
    }
    {
      int i = 16 + rb + r, j = 16 + jc;
      if (i <= j && j <= 26) op[128 + i * 27 - i * (i - 1) / 2 + (j - i)] = f2bf(a11[r]);
    }
  }
}

// ---------------- 128x256-tile phase-interleaved GEMM (2 blocks/CU), BK=32 ----------------
// 512 threads, wave grid 2M x 4N, wave tile 64x64, acc[4][4]. LDS 48KB:
// buf p @ p*24576: A[128][32] @ 0 (8KB), B[256][32] @ 8192 (16KB).
// Stage calls/wave: A=1, B=2. Guards: vmcnt(2).
__global__ __launch_bounds__(512, 4) void gemm_8ph_bm128(
    const __bf16* __restrict__ A, const __bf16* __restrict__ WT,
    const float* __restrict__ bias, __bf16* __restrict__ C,
    int N, int sA, int K, int gm)
{
  __shared__ __align__(16) char smem[49152];
  const int tid = threadIdx.x, lane = tid & 63, w = tid >> 6;
  const int wm = w >> 2, wn = w & 3;

  int nb = gridDim.x;
  int id = blockIdx.x;
  int swz = ((nb & 7) == 0) ? ((id & 7) * (nb >> 3) + (id >> 3)) : id;
  const int m0 = (swz % gm) * 128, n0 = (swz / gm) * 256;

  unsigned LdA; const __bf16* sApA;
  {
    unsigned L = (unsigned)w * 1024u + (unsigned)lane * 16u;
    unsigned Ls = swz16(L);
    LdA = L;
    sApA = A + (size_t)(m0 + (Ls >> 6)) * sA + ((Ls & 63) >> 1);
  }
  unsigned LdB[2]; const __bf16* sBp[2];
  #pragma unroll
  for (int h = 0; h < 2; ++h) {
    unsigned L = h * 8192u + (unsigned)w * 1024u + (unsigned)lane * 16u;
    unsigned Ls = swz16(L);
    LdB[h] = L;
    sBp[h] = WT + (size_t)(n0 + (Ls >> 6)) * K + ((Ls & 63) >> 1);
  }

  #define STAGE_A1(kt, p) { GLDS16(sApA + (kt)*32, smem + (p)*24576 + LdA); }
  #define STAGE_B2(kt, p) { GLDS16(sBp[0] + (kt)*32, smem + (p)*24576 + 8192 + LdB[0]); \
                            GLDS16(sBp[1] + (kt)*32, smem + (p)*24576 + 8192 + LdB[1]); }

  const unsigned cg = (lane >> 4) * 16u;
  const unsigned rA = (lane & 15);

  f32x4 acc[4][4] = {};
  const int iters = (K >> 5) >> 1;

  // prologue: B(0)[2], A(0)[1], B(1)[2]; guard tile 0 -> vmcnt(2)
  STAGE_B2(0, 0); STAGE_A1(0, 0); STAGE_B2(1, 1);
  asm volatile("s_waitcnt vmcnt(2)" ::: "memory");
  __builtin_amdgcn_s_barrier();
  __builtin_amdgcn_sched_barrier(0);

  for (int i = 0; i < iters; ++i) {
    const int t = 2 * i;
    const bool more = (i + 1 < iters);

    // ph0: tile t (buf0) m-frags 0,1 ; stage A(t+1)->buf1
    bf16x8 a0[2], b0[4];
    #pragma unroll
    for (int m = 0; m < 2; ++m) a0[m] = lds_frag(smem, 0, wm * 64 + m * 16 + rA, cg);
    #pragma unroll
    for (int n = 0; n < 4; ++n) b0[n] = lds_frag(smem, 8192, wn * 64 + n * 16 + rA, cg);
    STAGE_A1(t + 1, 1);
    __builtin_amdgcn_s_barrier();
    asm volatile("s_waitcnt lgkmcnt(0)" ::: "memory");
    __builtin_amdgcn_sched_barrier(0);
    __builtin_amdgcn_s_setprio(1);
    #pragma unroll
    for (int m = 0; m < 2; ++m)
      #pragma unroll
      for (int n = 0; n < 4; ++n)
        acc[m][n] = __builtin_amdgcn_mfma_f32_16x16x32_bf16(a0[m], b0[n], acc[m][n], 0, 0, 0);
    __builtin_amdgcn_s_setprio(0);
    __builtin_amdgcn_s_barrier();
    __builtin_amdgcn_sched_barrier(0);

    // ph1: tile t m-frags 2,3 ; stage B(t+2)->buf0 ; guard tile t+1
    bf16x8 a1[2];
    #pragma unroll
    for (int m = 0; m < 2; ++m) a1[m] = lds_frag(smem, 0, wm * 64 + 32 + m * 16 + rA, cg);
    if (more) STAGE_B2(t + 2, 0);
    __builtin_amdgcn_s_barrier();
    asm volatile("s_waitcnt lgkmcnt(0)" ::: "memory");
    __builtin_amdgcn_sched_barrier(0);
    __builtin_amdgcn_s_setprio(1);
    #pragma unroll
    for (int m = 0; m < 2; ++m)
      #pragma unroll
      for (int n = 0; n < 4; ++n)
        acc[2 + m][n] = __builtin_amdgcn_mfma_f32_16x16x32_bf16(a1[m], b0[n], acc[2 + m][n], 0, 0, 0);
    __builtin_amdgcn_s_setprio(0);
    if (more) { asm volatile("s_waitcnt vmcnt(2)" ::: "memory"); }
    else      { asm volatile("s_waitcnt vmcnt(0)" ::: "memory"); }
    __builtin_amdgcn_s_barrier();
    __builtin_amdgcn_sched_barrier(0);

    // ph2: tile t+1 (buf1) m-frags 0,1 ; stage A(t+2)->buf0
    bf16x8 a2[2], b2[4];
    #pragma unroll
    for (int m = 0; m < 2; ++m) a2[m] = lds_frag(smem, 24576, wm * 64 + m * 16 + rA, cg);
    #pragma unroll
    for (int n = 0; n < 4; ++n) b2[n] = lds_frag(smem, 24576 + 8192, wn * 64 + n * 16 + rA, cg);
    if (more) STAGE_A1(t + 2, 0);
    __builtin_amdgcn_s_barrier();
    asm volatile("s_waitcnt lgkmcnt(0)" ::: "memory");
    __builtin_amdgcn_sched_barrier(0);
    __builtin_amdgcn_s_setprio(1);
    #pragma unroll
    for (int m = 0; m < 2; ++m)
      #pragma unroll
      for (int n = 0; n < 4; ++n)
        acc[m][n] = __builtin_amdgcn_mfma_f32_16x16x32_bf16(a2[m], b2[n], acc[m][n], 0, 0, 0);
    __builtin_amdgcn_s_setprio(0);
    __builtin_amdgcn_s_barrier();
    __builtin_amdgcn_sched_barrier(0);

    // ph3: tile t+1 m-frags 2,3 ; stage B(t+3)->buf1 ; guard tile t+2
    bf16x8 a3[2];
    #pragma unroll
    for (int m = 0; m < 2; ++m) a3[m] = lds_frag(smem, 24576, wm * 64 + 32 + m * 16 + rA, cg);
    if (more) STAGE_B2(t + 3, 1);
    __builtin_amdgcn_s_barrier();
    asm volatile("s_waitcnt lgkmcnt(0)" ::: "memory");
    __builtin_amdgcn_sched_barrier(0);
    __builtin_amdgcn_s_setprio(1);
    #pragma unroll
    for (int m = 0; m < 2; ++m)
      #pragma unroll
      for (int n = 0; n < 4; ++n)
        acc[2 + m][n] = __builtin_amdgcn_mfma_f32_16x16x32_bf16(a3[m], b2[n], acc[2 + m][n], 0, 0, 0);
    __builtin_amdgcn_s_setprio(0);
    if (more) { asm volatile("s_waitcnt vmcnt(2)" ::: "memory"); }
    __builtin_amdgcn_s_barrier();
    __builtin_amdgcn_sched_barrier(0);
  }

  #pragma unroll
  for (int n = 0; n < 4; ++n) {
    int col = n0 + wn * 64 + n * 16 + (lane & 15);
    float bv = bias[col];
    #pragma unroll
    for (int m = 0; m < 4; ++m) {
      #pragma unroll
      for (int r = 0; r < 4; ++r) {
        int row = m0 + wm * 64 + m * 16 + (lane >> 4) * 4 + r;
        float v = fmaxf(acc[m][n][r] + bv, 0.f);
        C[(size_t)row * N + col] = f2bf(v);
      }
    }
  }
  #undef STAGE_A1
  #undef STAGE_B2
}

// ---------------- 256x128-tile phase-interleaved GEMM (t2) ----------------
__global__ __launch_bounds__(512, 2) void gemm_8ph_n128(
    const __bf16* __restrict__ A, const __bf16* __restrict__ WT,
    const float* __restrict__ bias, __bf16* __restrict__ C,
    int N, int sA, int K, int gm)
{
  __shared__ __align__(16) char smem[49152];
  const int tid = threadIdx.x, lane = tid & 63, w = tid >> 6;
  const int wm = w >> 1, wn = w & 1;

  int nb = gridDim.x;
  int id = blockIdx.x;
  int swz = ((nb & 7) == 0) ? ((id & 7) * (nb >> 3) + (id >> 3)) : id;
  const int m0 = (swz % gm) * 256, n0 = (swz / gm) * 128;

  unsigned Ld[2]; const __bf16* sAp[2]; const __bf16* sBp0;
  #pragma unroll
  for (int h = 0; h < 2; ++h) {
    unsigned L = h * 8192u + (unsigned)w * 1024u + (unsigned)lane * 16u;
    unsigned Ls = swz16(L);
    Ld[h] = L;
    int srow = Ls >> 6, scb = Ls & 63;
    sAp[h] = A + (size_t)(m0 + srow) * sA + (scb >> 1);
  }
  {
    unsigned L = (unsigned)w * 1024u + (unsigned)lane * 16u;
    unsigned Ls = swz16(L);
    int srow = Ls >> 6, scb = Ls & 63;
    sBp0 = WT + (size_t)(n0 + srow) * K + (scb >> 1);
  }

  #define STAGE_A2(kt, p) { GLDS16(sAp[0] + (kt)*32, smem + (p)*24576 + Ld[0]); \
                            GLDS16(sAp[1] + (kt)*32, smem + (p)*24576 + Ld[1]); }
  #define STAGE_B1(kt, p) { GLDS16(sBp0 + (kt)*32, smem + (p)*24576 + 16384 + Ld[0]); }

  const unsigned cg = (lane >> 4) * 16u;
  const unsigned rA = (lane & 15);

  f32x4 acc[4][4] = {};
  const int iters = (K >> 5) >> 1;

  STAGE_B1(0, 0); STAGE_A2(0, 0); STAGE_B1(1, 1);
  asm volatile("s_waitcnt vmcnt(1)" ::: "memory");
  __builtin_amdgcn_s_barrier();
  __builtin_amdgcn_sched_barrier(0);

  for (int i = 0; i < iters; ++i) {
    const int t = 2 * i;
    const bool more = (i + 1 < iters);

    bf16x8 a0[2], b0[4];
    #pragma unroll
    for (int m = 0; m < 2; ++m) a0[m] = lds_frag(smem, 0, wm * 64 + m * 16 + rA, cg);
    #pragma unroll
    for (int n = 0; n < 4; ++n) b0[n] = lds_frag(smem, 16384, wn * 64 + n * 16 + rA, cg);
    STAGE_A2(t + 1, 1);
    __builtin_amdgcn_s_barrier();
    asm volatile("s_waitcnt lgkmcnt(0)" ::: "memory");
    __builtin_amdgcn_sched_barrier(0);
    __builtin_amdgcn_s_setprio(1);
    #pragma unroll
    for (int m = 0; m < 2; ++m)
      #pragma unroll
      for (int n = 0; n < 4; ++n)
        acc[m][n] = __builtin_amdgcn_mfma_f32_16x16x32_bf16(a0[m], b0[n], acc[m][n], 0, 0, 0);
    __builtin_amdgcn_s_setprio(0);
    __builtin_amdgcn_s_barrier();
    __builtin_amdgcn_sched_barrier(0);

    bf16x8 a1[2];
    #pragma unroll
    for (int m = 0; m < 2; ++m) a1[m] = lds_frag(smem, 0, wm * 64 + 32 + m * 16 + rA, cg);
    if (more) STAGE_B1(t + 2, 0);
    __builtin_amdgcn_s_barrier();
    asm volatile("s_waitcnt lgkmcnt(0)" ::: "memory");
    __builtin_amdgcn_sched_barrier(0);
    __builtin_amdgcn_s_setprio(1);
    #pragma unroll
    for (int m = 0; m < 2; ++m)
      #pragma unroll
      for (int n = 0; n < 4; ++n)
        acc[2 + m][n] = __builtin_amdgcn_mfma_f32_16x16x32_bf16(a1[m], b0[n], acc[2 + m][n], 0, 0, 0);
    __builtin_amdgcn_s_setprio(0);
    if (more) { asm volatile("s_waitcnt vmcnt(1)" ::: "memory"); }
    else      { asm volatile("s_waitcnt vmcnt(0)" ::: "memory"); }
    __builtin_amdgcn_s_barrier();
    __builtin_amdgcn_sched_barrier(0);

    bf16x8 a2[2], b2[4];
    #pragma unroll
    for (int m = 0; m < 2; ++m) a2[m] = lds_frag(smem, 24576, wm * 64 + m * 16 + rA, cg);
    #pragma unroll
    for (int n = 0; n < 4; ++n) b2[n] = lds_frag(smem, 24576 + 16384, wn * 64 + n * 16 + rA, cg);
    if (more) STAGE_A2(t + 2, 0);
    __builtin_amdgcn_s_barrier();
    asm volatile("s_waitcnt lgkmcnt(0)" ::: "memory");
    __builtin_amdgcn_sched_barrier(0);
    __builtin_amdgcn_s_setprio(1);
    #pragma unroll
    for (int m = 0; m < 2; ++m)
      #pragma unroll
      for (int n = 0; n < 4; ++n)
        acc[m][n] = __builtin_amdgcn_mfma_f32_16x16x32_bf16(a2[m], b2[n], acc[m][n], 0, 0, 0);
    __builtin_amdgcn_s_setprio(0);
    __builtin_amdgcn_s_barrier();
    __builtin_amdgcn_sched_barrier(0);

    bf16x8 a3[2];
    #pragma unroll
    for (int m = 0; m < 2; ++m) a3[m] = lds_frag(smem, 24576, wm * 64 + 32 + m * 16 + rA, cg);
    if (more) STAGE_B1(t + 3, 1);
    __builtin_amdgcn_s_barrier();
    asm volatile("s_waitcnt lgkmcnt(0)" ::: "memory");
    __builtin_amdgcn_sched_barrier(0);
    __builtin_amdgcn_s_setprio(1);
    #pragma unroll
    for (int m = 0; m < 2; ++m)
      #pragma unroll
      for (int n = 0; n < 4; ++n)
        acc[2 + m][n] = __builtin_amdgcn_mfma_f32_16x16x32_bf16(a3[m], b2[n], acc[2 + m][n], 0, 0, 0);
    __builtin_amdgcn_s_setprio(0);
    if (more) { asm volatile("s_waitcnt vmcnt(1)" ::: "memory"); }
    __builtin_amdgcn_s_barrier();
    __builtin_amdgcn_sched_barrier(0);
  }

  #pragma unroll
  for (int n = 0; n < 4; ++n) {
    int col = n0 + wn * 64 + n * 16 + (lane & 15);
    float bv = bias[col];
    #pragma unroll
    for (int m = 0; m < 4; ++m) {
      #pragma unroll
      for (int r = 0; r < 4; ++r) {
        int row = m0 + wm * 64 + m * 16 + (lane >> 4) * 4 + r;
        float v = fmaxf(acc[m][n][r] + bv, 0.f);
        C[(size_t)row * N + col] = f2bf(v);
      }
    }
  }
  #undef STAGE_A2
  #undef STAGE_B1
}

// ---------------- fused t3 GEMM (128x256 tile, N=256 K=512) + final dot ----------------
__global__ __launch_bounds__(256) void gemm_t3_final(
    const __bf16* __restrict__ A, const __bf16* __restrict__ WT,
    const float* __restrict__ b3, const float* __restrict__ w4,
    const float* __restrict__ b4, float* __restrict__ out)
{
  __shared__ __bf16 As[128][32];
  __shared__ __bf16 Bs[256][32];
  __shared__ float red[128][4];
  const int tid = threadIdx.x, lane = tid & 63, wid = tid >> 6;
  const int m0 = blockIdx.x * 128;
  const int srow = wid * 16 + (lane >> 2);
  const int scol = (lane & 3) * 8;
  const __bf16* Ag0 = A + (size_t)(m0 + srow) * 512 + scol;
  const __bf16* Ag1 = A + (size_t)(m0 + srow + 64) * 512 + scol;

  f32x4 acc[8][4] = {};

  for (int k0 = 0; k0 < 512; k0 += 32) {
    __syncthreads();
    GLDS16(Ag0 + k0, &As[srow][scol]);
    GLDS16(Ag1 + k0, &As[srow + 64][scol]);
    #pragma unroll
    for (int c = 0; c < 4; ++c) {
      int br = wid * 64 + c * 16 + (lane >> 2);
      GLDS16(WT + (size_t)br * 512 + k0 + scol, &Bs[br][scol]);
    }
    __syncthreads();

    bf16x8 af[8], bfv[4];
    #pragma unroll
    for (int m = 0; m < 8; ++m)
      af[m] = *(const bf16x8*)&As[m * 16 + (lane & 15)][(lane >> 4) * 8];
    #pragma unroll
    for (int n = 0; n < 4; ++n)
      bfv[n] = *(const bf16x8*)&Bs[wid * 64 + n * 16 + (lane & 15)][(lane >> 4) * 8];
    #pragma unroll
    for (int m = 0; m < 8; ++m)
      #pragma unroll
      for (int n = 0; n < 4; ++n)
        acc[m][n] = __builtin_amdgcn_mfma_f32_16x16x32_bf16(af[m], bfv[n], acc[m][n], 0, 0, 0);
  }

  float pd[8][4];
  #pragma unroll
  for (int m = 0; m < 8; ++m)
    #pragma unroll
    for (int r = 0; r < 4; ++r) pd[m][r] = 0.f;
  #pragma unroll
  for (int n = 0; n < 4; ++n) {
    int col = wid * 64 + n * 16 + (lane & 15);
    float bb = b3[col];
    float wc = w4[col];
    #pragma unroll
    for (int m = 0; m < 8; ++m)
      #pragma unroll
      for (int r = 0; r < 4; ++r)
        pd[m][r] += fmaxf(acc[m][n][r] + bb, 0.f) * wc;
  }
  #pragma unroll
  for (int m = 0; m < 8; ++m)
    #pragma unroll
    for (int r = 0; r < 4; ++r) {
      float s = pd[m][r];
      s += __shfl_xor(s, 1); s += __shfl_xor(s, 2);
      s += __shfl_xor(s, 4); s += __shfl_xor(s, 8);
      if ((lane & 15) == 0) red[m * 16 + (lane >> 4) * 4 + r][wid] = s;
    }
  __syncthreads();
  if (tid < 128)
    out[m0 + tid] = red[tid][0] + red[tid][1] + red[tid][2] + red[tid][3] + b4[0];
}

extern "C" void kernel_launch(void* const* d_in, const int* in_sizes, int n_in,
                              void* d_out, int out_size, void* d_ws, size_t ws_size,
                              hipStream_t stream)
{
  const float* x_dense = (const float*)d_in[0];
  const int*   x_cat   = (const int*)d_in[1];
  const float* emb     = (const float*)d_in[2];
  const float* wb[3] = {(const float*)d_in[3], (const float*)d_in[5], (const float*)d_in[7]};
  const float* bb[3] = {(const float*)d_in[4], (const float*)d_in[6], (const float*)d_in[8]};
  const float* wt[5] = {(const float*)d_in[9],  (const float*)d_in[11], (const float*)d_in[13],
                        (const float*)d_in[15], (const float*)d_in[17]};
  const float* bt[5] = {(const float*)d_in[10], (const float*)d_in[12], (const float*)d_in[14],
                        (const float*)d_in[16], (const float*)d_in[18]};
  float* out = (float*)d_out;

  char* ws = (char*)d_ws;
  const size_t MB = 1ull << 20;
  __bf16* wt_b0 = (__bf16*)(ws + 0 * MB);   // 512x32
  __bf16* wt_b1 = (__bf16*)(ws + 1 * MB);   // 256x512
  __bf16* wt_b2 = (__bf16*)(ws + 2 * MB);   // 128x256
  __bf16* wt_t0 = (__bf16*)(ws + 3 * MB);   // 1024x512
  __bf16* wt_t1 = (__bf16*)(ws + 4 * MB);   // 1024x1024
  __bf16* wt_t2 = (__bf16*)(ws + 6 * MB);   // 512x1024
  __bf16* wt_t3 = (__bf16*)(ws + 7 * MB);   // 256x512
  __bf16* h2     = (__bf16*)(ws + 8 * MB);   // 16384x128 = 4MB
  __bf16* top_in = (__bf16*)(ws + 12 * MB);  // 16MB (region C)
  __bf16* t2     = (__bf16*)(ws + 12 * MB);  // (region C, after top_in dead)
  __bf16* t1     = (__bf16*)(ws + 28 * MB);  // 32MB (region A)
  __bf16* t0     = (__bf16*)(ws + 60 * MB);  // 32MB (region B)

  // ---- fused weight prep (1 dispatch) ----
  TJobs js;
  const float* Ws[7] = {wb[0], wb[1], wb[2], wt[0], wt[1], wt[2], wt[3]};
  __bf16* WTs[7] = {wt_b0, wt_b1, wt_b2, wt_t0, wt_t1, wt_t2, wt_t3};
  int Ks[7]  = {13, 512, 256, 506, 1024, 1024, 512};
  int Ns[7]  = {512, 256, 128, 1024, 1024, 512, 256};
  int Kps[7] = {32, 512, 256, 512, 1024, 1024, 512};
  int off = 0;
  for (int i = 0; i < 7; ++i) {
    int tx = (Kps[i] + 63) / 64, ty = (Ns[i] + 63) / 64;
    js.j[i] = TJob{Ws[i], WTs[i], Ks[i], Ns[i], Kps[i], tx, off};
    off += tx * ty;
  }
  transpose_all<<<dim3(off), dim3(256), 0, stream>>>(js, 7);

  // ---- fused bottom MLP ----
  bottom_fused<<<dim3(BATCH / 32), dim3(256), 0, stream>>>(
      x_dense, wt_b0, bb[0], wt_b1, bb[1], wt_b2, bb[2], h2);

  // ---- embedding + interaction ----
  interact_mfma<<<dim3(BATCH / 4), dim3(256), 0, stream>>>(h2, x_cat, emb, top_in);

  // ---- top MLP ----
  gemm_8ph_bm128<<<dim3(512), dim3(512), 0, stream>>>(top_in, wt_t0, bt[0], t0, 1024, 512, 512, 128);
  gemm_8ph_bm128<<<dim3(512), dim3(512), 0, stream>>>(t0, wt_t1, bt[1], t1, 1024, 1024, 1024, 128);
  gemm_8ph_n128<<<dim3(256), dim3(512), 0, stream>>>(t1, wt_t2, bt[2], t2, 512, 1024, 1024, 64);

  // ---- fused t3 + final ----
  gemm_t3_final<<<dim3(128), dim3(256), 0, stream>>>(t2, wt_t3, bt[3], wt[4], bt[4], out);
}